// Round 1
// baseline (1342.204 us; speedup 1.0000x reference)
//
#include <hip/hip_runtime.h>
#include <cstdint>
#include <cstddef>
#include <cmath>

#define EPS_COS 1e-8f

// ---------------------------------------------------------------------------
// row L2 norms (C fixed = 1024)
// ---------------------------------------------------------------------------
__global__ __launch_bounds__(256) void norm_rows_kernel(const float* __restrict__ X,
                                                        float* __restrict__ out) {
    int r = blockIdx.x;
    int t = threadIdx.x;
    const float4 v = *reinterpret_cast<const float4*>(&X[(size_t)r * 1024 + t * 4]);
    float ss = v.x * v.x + v.y * v.y + v.z * v.z + v.w * v.w;
#pragma unroll
    for (int off = 32; off > 0; off >>= 1) ss += __shfl_down(ss, off);
    __shared__ float red[4];
    int wave = t >> 6, lane = t & 63;
    if (lane == 0) red[wave] = ss;
    __syncthreads();
    if (t == 0) out[r] = sqrtf(red[0] + red[1] + red[2] + red[3]);
}

// ---------------------------------------------------------------------------
// generic fp32 tiled GEMM: C[M,N] = A[M,K] * B
//   B_TRANS=1: B stored [N,K] row-major (NT form, used for dots = z @ protos^T)
//   B_TRANS=0: B stored [K,N] row-major (NN form)
//   A_CAT: A = concat(A0, A1) along K, each half row-stride lda (=1024)
//   EPI=0: plain store; EPI=1: gate = sigmoid(acc + bias), C = g*z + (1-g)*z_hat
// tiles: BM=BN=64, BK=16, 256 threads, 4x4 per thread
// ---------------------------------------------------------------------------
template <bool B_TRANS, int EPI, bool A_CAT>
__global__ __launch_bounds__(256) void gemm_kernel(
    const float* __restrict__ A0, const float* __restrict__ A1, int lda,
    const float* __restrict__ B, float* __restrict__ C, int M, int N, int K,
    const float* __restrict__ ebias, const float* __restrict__ ez,
    const float* __restrict__ ezh) {
    __shared__ float As[16][68];
    __shared__ float Bs[16][68];
    const int t = threadIdx.x;
    const int m0 = blockIdx.x * 64;
    const int n0 = blockIdx.y * 64;
    const int tm = t >> 4, tn = t & 15;
    const int lrow = t >> 2;        // 0..63
    const int lk = (t & 3) << 2;    // 0,4,8,12
    float acc[4][4] = {{0.0f}};

    for (int k0 = 0; k0 < K; k0 += 16) {
        // A tile -> As[k][m] (transposed in LDS)
        {
            const float* Ab = A0;
            int col = k0 + lk;
            if (A_CAT) {
                if (k0 >= lda) { Ab = A1; col = k0 - lda + lk; }
            }
            float4 v = *reinterpret_cast<const float4*>(&Ab[(size_t)(m0 + lrow) * lda + col]);
            As[lk + 0][lrow] = v.x;
            As[lk + 1][lrow] = v.y;
            As[lk + 2][lrow] = v.z;
            As[lk + 3][lrow] = v.w;
        }
        if (B_TRANS) {
            float4 v = *reinterpret_cast<const float4*>(&B[(size_t)(n0 + lrow) * K + k0 + lk]);
            Bs[lk + 0][lrow] = v.x;
            Bs[lk + 1][lrow] = v.y;
            Bs[lk + 2][lrow] = v.z;
            Bs[lk + 3][lrow] = v.w;
        } else {
            int kl = t >> 4;          // 0..15
            int nl = (t & 15) << 2;   // 0..60
            float4 v = *reinterpret_cast<const float4*>(&B[(size_t)(k0 + kl) * N + n0 + nl]);
            *reinterpret_cast<float4*>(&Bs[kl][nl]) = v;
        }
        __syncthreads();
#pragma unroll
        for (int kk = 0; kk < 16; ++kk) {
            float4 a4 = *reinterpret_cast<const float4*>(&As[kk][tm << 2]);
            float4 b4 = *reinterpret_cast<const float4*>(&Bs[kk][tn << 2]);
            float av[4] = {a4.x, a4.y, a4.z, a4.w};
            float bv[4] = {b4.x, b4.y, b4.z, b4.w};
#pragma unroll
            for (int i = 0; i < 4; ++i)
#pragma unroll
                for (int j = 0; j < 4; ++j) acc[i][j] = fmaf(av[i], bv[j], acc[i][j]);
        }
        __syncthreads();
    }
#pragma unroll
    for (int i = 0; i < 4; ++i) {
        int row = m0 + (tm << 2) + i;
        int col = n0 + (tn << 2);
        if (EPI == 0) {
            *reinterpret_cast<float4*>(&C[(size_t)row * N + col]) =
                make_float4(acc[i][0], acc[i][1], acc[i][2], acc[i][3]);
        } else {
            float4 zv = *reinterpret_cast<const float4*>(&ez[(size_t)row * N + col]);
            float4 hv = *reinterpret_cast<const float4*>(&ezh[(size_t)row * N + col]);
            float4 bb = *reinterpret_cast<const float4*>(&ebias[col]);
            float zz[4] = {zv.x, zv.y, zv.z, zv.w};
            float hh[4] = {hv.x, hv.y, hv.z, hv.w};
            float bv[4] = {bb.x, bb.y, bb.z, bb.w};
            float ov[4];
#pragma unroll
            for (int j = 0; j < 4; ++j) {
                float pre = acc[i][j] + bv[j];
                float g = 1.0f / (1.0f + expf(-pre));
                ov[j] = g * zz[j] + (1.0f - g) * hh[j];
            }
            *reinterpret_cast<float4*>(&C[(size_t)row * N + col]) =
                make_float4(ov[0], ov[1], ov[2], ov[3]);
        }
    }
}

// ---------------------------------------------------------------------------
// softmax over K=512 with cosine scaling: sim = dots / max(zn*pn, eps)
// one block per row; writes attn
// ---------------------------------------------------------------------------
__global__ __launch_bounds__(256) void softmax_kernel(const float* __restrict__ dots,
                                                      const float* __restrict__ zn,
                                                      const float* __restrict__ pn,
                                                      float* __restrict__ attn) {
    int m = blockIdx.x;
    int t = threadIdx.x;
    float zm = zn[m];
    float d0 = dots[(size_t)m * 512 + t];
    float d1 = dots[(size_t)m * 512 + t + 256];
    float v0 = d0 / fmaxf(zm * pn[t], EPS_COS);
    float v1 = d1 / fmaxf(zm * pn[t + 256], EPS_COS);
    float mx = fmaxf(v0, v1);
#pragma unroll
    for (int off = 32; off > 0; off >>= 1) mx = fmaxf(mx, __shfl_down(mx, off));
    __shared__ float red[8];
    int wave = t >> 6, lane = t & 63;
    if (lane == 0) red[wave] = mx;
    __syncthreads();
    if (t == 0) red[4] = fmaxf(fmaxf(red[0], red[1]), fmaxf(red[2], red[3]));
    __syncthreads();
    mx = red[4];
    float e0 = expf(v0 - mx), e1 = expf(v1 - mx);
    float s = e0 + e1;
#pragma unroll
    for (int off = 32; off > 0; off >>= 1) s += __shfl_down(s, off);
    if (lane == 0) red[wave] = s;
    __syncthreads();
    if (t == 0) red[5] = 1.0f / (red[0] + red[1] + red[2] + red[3]);
    __syncthreads();
    float r = red[5];
    attn[(size_t)m * 512 + t] = e0 * r;
    attn[(size_t)m * 512 + t + 256] = e1 * r;
}

// ---------------------------------------------------------------------------
// pooled[b,d] = mean_n z_fused[b,n,d]
// ---------------------------------------------------------------------------
__global__ __launch_bounds__(256) void pool_kernel(const float* __restrict__ zf,
                                                   float* __restrict__ pooled) {
    int idx = blockIdx.x * 256 + threadIdx.x;  // 32768
    int b = idx >> 10, d = idx & 1023;
    const float* p = zf + (size_t)b * 196 * 1024 + d;
    float s = 0.0f;
    for (int n = 0; n < 196; ++n) s += p[(size_t)n * 1024];
    pooled[idx] = s / 196.0f;
}

// ---------------------------------------------------------------------------
// h[b,c] = pooled[b,:] @ dec_w[:,c] + dec_b[c]   (c < 25088, memory-bound)
// 64 threads/block, 1 column each, 32 batch accumulators (pooled loads are
// thread-uniform -> scalar loads)
// ---------------------------------------------------------------------------
__global__ __launch_bounds__(64) void dec_kernel(const float* __restrict__ pooled,
                                                 const float* __restrict__ dec_w,
                                                 const float* __restrict__ dec_b,
                                                 float* __restrict__ h) {
    int c = blockIdx.x * 64 + threadIdx.x;
    float acc[32];
    float bb = dec_b[c];
#pragma unroll
    for (int b = 0; b < 32; ++b) acc[b] = bb;
    for (int k = 0; k < 1024; ++k) {
        float wv = dec_w[(size_t)k * 25088 + c];
#pragma unroll
        for (int b = 0; b < 32; ++b) acc[b] = fmaf(pooled[b * 1024 + k], wv, acc[b]);
    }
#pragma unroll
    for (int b = 0; b < 32; ++b) h[(size_t)b * 25088 + c] = acc[b];
}

// ---------------------------------------------------------------------------
// ct1_w [ic=512][oc=256][ky=4][kx=4] -> wt [class p=4][tap=4][ic=512][oc=256]
// class p=(py,px): ky=(1-py)+2*ty, kx=(1-px)+2*tx
// ---------------------------------------------------------------------------
__global__ __launch_bounds__(256) void wtrans_kernel(const float* __restrict__ wsrc,
                                                     float* __restrict__ wt) {
    int idx = blockIdx.x * 256 + threadIdx.x;  // ic*256+oc, 131072
    int oc = idx & 255, ic = idx >> 8;
    float v[16];
#pragma unroll
    for (int i = 0; i < 16; ++i) v[i] = wsrc[(size_t)idx * 16 + i];
#pragma unroll
    for (int pp = 0; pp < 4; ++pp) {
        int py = pp >> 1, px = pp & 1;
#pragma unroll
        for (int tap = 0; tap < 4; ++tap) {
            int ty = tap >> 1, tx = tap & 1;
            int ky = (1 - py) + 2 * ty;
            int kx = (1 - px) + 2 * tx;
            wt[((size_t)(pp * 4 + tap) * 512 + ic) * 256 + oc] = v[ky * 4 + kx];
        }
    }
}

// ---------------------------------------------------------------------------
// ConvTranspose2d(512->256, k4, s2, p1) + bias + relu, via parity classes.
// out[b,oc,2*sy+py,2*sx+px] = sum_ic sum_{ty,tx} h[b,ic,sy+py-ty,sx+px-tx]
//                             * w[ic,oc,(1-py)+2ty,(1-px)+2tx]
// grid (oct=4, p=4, b=32), 128 threads: og=t&7 (8 oc), sg=t>>3 (2x2 spatial)
// h staged in LDS with a zero border (9x9) so the inner loop has no masks.
// ---------------------------------------------------------------------------
#define ICC 32
__global__ __launch_bounds__(128) void convt1_kernel(const float* __restrict__ h,
                                                     const float* __restrict__ wt,
                                                     const float* __restrict__ bias,
                                                     float* __restrict__ out) {
    const int oct = blockIdx.x;  // oc tile of 64
    const int p = blockIdx.y;
    const int b = blockIdx.z;
    const int py = p >> 1, px = p & 1;
    const int t = threadIdx.x;  // 0..127
    const int og = t & 7;       // 8 groups x 8 oc = 64
    const int sg = t >> 3;      // 0..15
    const int sgy = sg >> 2, sgx = sg & 3;

    __shared__ float hs[ICC][100];   // 9x9 zero-padded (stride 9), zero slack to 100
    __shared__ float ws[4][ICC][64];

    for (int l = t; l < ICC * 100; l += 128) ((float*)hs)[l] = 0.0f;

    float acc[4][8];
#pragma unroll
    for (int i = 0; i < 4; ++i)
#pragma unroll
        for (int j = 0; j < 8; ++j) acc[i][j] = 0.0f;

    const float* hb = h + (size_t)b * 25088;
    const int R0 = 2 * sgy + py;
    const int C0 = 2 * sgx + px;

    for (int ic0 = 0; ic0 < 512; ic0 += ICC) {
        __syncthreads();
        for (int l = t; l < ICC * 49; l += 128) {
            int i = l / 49, s = l - i * 49;
            int sy = s / 7, sx = s - sy * 7;
            hs[i][(sy + 1) * 9 + sx + 1] = hb[(size_t)(ic0 + i) * 49 + s];
        }
        for (int l = t; l < 4 * ICC * 64; l += 128) {
            int tap = l >> 11;
            int i = (l >> 6) & 31;
            int ol = l & 63;
            ws[tap][i][ol] =
                wt[((size_t)(p * 4 + tap) * 512 + ic0 + i) * 256 + oct * 64 + ol];
        }
        __syncthreads();
        for (int i = 0; i < ICC; ++i) {
            float hv[3][3];
#pragma unroll
            for (int ri = 0; ri < 3; ++ri)
#pragma unroll
                for (int ci = 0; ci < 3; ++ci)
                    hv[ri][ci] = hs[i][(R0 + ri) * 9 + (C0 + ci)];
#pragma unroll
            for (int tap = 0; tap < 4; ++tap) {
                int ty = tap >> 1, tx = tap & 1;
                float4 w0 = *reinterpret_cast<const float4*>(&ws[tap][i][og * 8]);
                float4 w1 = *reinterpret_cast<const float4*>(&ws[tap][i][og * 8 + 4]);
                float w[8] = {w0.x, w0.y, w0.z, w0.w, w1.x, w1.y, w1.z, w1.w};
#pragma unroll
                for (int dy = 0; dy < 2; ++dy)
#pragma unroll
                    for (int dx = 0; dx < 2; ++dx) {
                        float hvv = hv[dy - ty + 1][dx - tx + 1];
#pragma unroll
                        for (int j = 0; j < 8; ++j)
                            acc[dy * 2 + dx][j] = fmaf(hvv, w[j], acc[dy * 2 + dx][j]);
                    }
            }
        }
    }
#pragma unroll
    for (int dy = 0; dy < 2; ++dy) {
        int sy = 2 * sgy + dy;
        if (sy >= 7) continue;
        int oy = 2 * sy + py;
#pragma unroll
        for (int dx = 0; dx < 2; ++dx) {
            int sx = 2 * sgx + dx;
            if (sx >= 7) continue;
            int ox = 2 * sx + px;
#pragma unroll
            for (int j = 0; j < 8; ++j) {
                int oc = oct * 64 + og * 8 + j;
                float v = acc[dy * 2 + dx][j] + bias[oc];
                out[(((size_t)b * 256 + oc) * 14 + oy) * 14 + ox] = fmaxf(v, 0.0f);
            }
        }
    }
}

// ---------------------------------------------------------------------------
// ConvTranspose2d(256->3, k4, s2, p1) + bias. One thread per output element.
// ---------------------------------------------------------------------------
__global__ __launch_bounds__(256) void convt2_kernel(const float* __restrict__ h2,
                                                     const float* __restrict__ w,
                                                     const float* __restrict__ bias,
                                                     float* __restrict__ out) {
    int o = blockIdx.x * 256 + threadIdx.x;  // < 75264
    int ox = o % 28;
    int oy = (o / 28) % 28;
    int oc = (o / 784) % 3;
    int b = o / 2352;
    float acc = bias[oc];
    int ky0 = (oy + 1) & 1, kx0 = (ox + 1) & 1;
    const float* hbase = h2 + (size_t)b * 256 * 196;
#pragma unroll
    for (int tt = 0; tt < 4; ++tt) {
        int ky = ky0 + 2 * (tt >> 1);
        int kx = kx0 + 2 * (tt & 1);
        int iy = (oy + 1 - ky) >> 1;
        int ix = (ox + 1 - kx) >> 1;
        if ((unsigned)iy < 14u && (unsigned)ix < 14u) {
            const float* hp = hbase + iy * 14 + ix;
            const float* wp = w + oc * 16 + ky * 4 + kx;
            for (int ic = 0; ic < 256; ++ic)
                acc = fmaf(hp[(size_t)ic * 196], wp[ic * 48], acc);
        }
    }
    out[o] = acc;
}

// ---------------------------------------------------------------------------
extern "C" void kernel_launch(void* const* d_in, const int* in_sizes, int n_in,
                              void* d_out, int out_size, void* d_ws, size_t ws_size,
                              hipStream_t stream) {
    const float* z      = (const float*)d_in[0];  // [32,196,1024]
    const float* protos = (const float*)d_in[1];  // [512,1024]
    const float* gate_w = (const float*)d_in[2];  // [2048,1024]
    const float* gate_b = (const float*)d_in[3];  // [1024]
    const float* dec_w  = (const float*)d_in[4];  // [1024,25088]
    const float* dec_b  = (const float*)d_in[5];  // [25088]
    const float* ct1_w  = (const float*)d_in[6];  // [512,256,4,4]
    const float* ct1_b  = (const float*)d_in[7];  // [256]
    const float* ct2_w  = (const float*)d_in[8];  // [256,3,4,4]
    const float* ct2_b  = (const float*)d_in[9];  // [3]

    float* xout = (float*)d_out;    // x_recon [32,3,28,28] = 75264
    float* attn = xout + 75264;     // attn [32,196,512] = 3211264

    float* w = (float*)d_ws;
    float* pn      = w;              // 512
    float* zn      = w + 512;        // 6272
    float* dots    = w + 6784;       // 3,211,264
    float* z_hat   = w + 3218048;    // 6,422,528
    float* z_fused = w + 9640576;    // 6,422,528
    float* pooled  = w + 16063104;   // 32,768
    float* hbuf    = w + 16095872;   // 802,816
    float* h2      = w + 16898688;   // 1,605,632
    float* wt1     = w + 18504320;   // 2,097,152  (total 20,601,472 floats = 82.4 MB)

    // norms
    norm_rows_kernel<<<512, 256, 0, stream>>>(protos, pn);
    norm_rows_kernel<<<6272, 256, 0, stream>>>(z, zn);
    // dots = z @ protos^T  (NT)
    gemm_kernel<true, 0, false><<<dim3(98, 8), 256, 0, stream>>>(
        z, nullptr, 1024, protos, dots, 6272, 512, 1024, nullptr, nullptr, nullptr);
    // sim scale + softmax -> attn (written straight into d_out)
    softmax_kernel<<<6272, 256, 0, stream>>>(dots, zn, pn, attn);
    // z_hat = attn @ protos (NN)
    gemm_kernel<false, 0, false><<<dim3(98, 16), 256, 0, stream>>>(
        attn, nullptr, 512, protos, z_hat, 6272, 1024, 512, nullptr, nullptr, nullptr);
    // gate GEMM + sigmoid + blend -> z_fused
    gemm_kernel<false, 1, true><<<dim3(98, 16), 256, 0, stream>>>(
        z, z_hat, 1024, gate_w, z_fused, 6272, 1024, 2048, gate_b, z, z_hat);
    // pooled mean over tokens
    pool_kernel<<<128, 256, 0, stream>>>(z_fused, pooled);
    // decoder linear
    dec_kernel<<<392, 64, 0, stream>>>(pooled, dec_w, dec_b, hbuf);
    // conv-transpose 1 (weight transpose once per launch, then parity-class conv)
    wtrans_kernel<<<512, 256, 0, stream>>>(ct1_w, wt1);
    convt1_kernel<<<dim3(4, 4, 32), 128, 0, stream>>>(hbuf, wt1, ct1_b, h2);
    // conv-transpose 2 -> x_recon
    convt2_kernel<<<294, 256, 0, stream>>>(h2, ct2_w, ct2_b, xout);
}

// Round 2
// 724.088 us; speedup vs baseline: 1.8536x; 1.8536x over previous
//
#include <hip/hip_runtime.h>
#include <cstdint>
#include <cstddef>
#include <cmath>

#define EPS_COS 1e-8f

typedef unsigned short u16;
typedef __attribute__((ext_vector_type(8))) short short8v;
typedef __attribute__((ext_vector_type(4))) float f32x4;

__device__ __forceinline__ u16 f2bf(float x) {
    unsigned int u = __float_as_uint(x);
    return (u16)((u + 0x7FFFu + ((u >> 16) & 1u)) >> 16);  // RNE
}
__device__ __forceinline__ float bf2f(u16 h) {
    return __uint_as_float(((unsigned int)h) << 16);
}

// ---------------------------------------------------------------------------
// row L2 norms (C fixed = 1024)
// ---------------------------------------------------------------------------
__global__ __launch_bounds__(256) void norm_rows_kernel(const float* __restrict__ X,
                                                        float* __restrict__ out) {
    int r = blockIdx.x;
    int t = threadIdx.x;
    const float4 v = *reinterpret_cast<const float4*>(&X[(size_t)r * 1024 + t * 4]);
    float ss = v.x * v.x + v.y * v.y + v.z * v.z + v.w * v.w;
#pragma unroll
    for (int off = 32; off > 0; off >>= 1) ss += __shfl_down(ss, off);
    __shared__ float red[4];
    int wave = t >> 6, lane = t & 63;
    if (lane == 0) red[wave] = ss;
    __syncthreads();
    if (t == 0) out[r] = sqrtf(red[0] + red[1] + red[2] + red[3]);
}

// ---------------------------------------------------------------------------
// fp32 -> bf16 copy (row-strided dst), 8 elems/thread
// ---------------------------------------------------------------------------
__global__ __launch_bounds__(256) void cvt_bf_kernel(const float* __restrict__ src,
                                                     u16* __restrict__ dst,
                                                     int srcW, int dstStride, int nElem) {
    int idx = blockIdx.x * 256 + threadIdx.x;
    int e = idx * 8;
    if (e >= nElem) return;
    float4 v0 = *reinterpret_cast<const float4*>(src + e);
    float4 v1 = *reinterpret_cast<const float4*>(src + e + 4);
    int row = e / srcW, col = e - row * srcW;
    u16* d = dst + (size_t)row * dstStride + col;
    short8v o;
    o[0] = f2bf(v0.x); o[1] = f2bf(v0.y); o[2] = f2bf(v0.z); o[3] = f2bf(v0.w);
    o[4] = f2bf(v1.x); o[5] = f2bf(v1.y); o[6] = f2bf(v1.z); o[7] = f2bf(v1.w);
    *reinterpret_cast<short8v*>(d) = o;
}

// ---------------------------------------------------------------------------
// transpose + cvt: src [R][C] f32 -> dst [C][R] bf16 (64x64 LDS tiles, +1 pad)
// ---------------------------------------------------------------------------
__global__ __launch_bounds__(256) void transpose_cvt_kernel(const float* __restrict__ src,
                                                            u16* __restrict__ dst,
                                                            int R, int C) {
    __shared__ float tile[64][65];
    int c0 = blockIdx.x * 64, r0 = blockIdx.y * 64;
    int t = threadIdx.x;
#pragma unroll
    for (int j = 0; j < 16; ++j) {
        int idx = j * 256 + t;
        int r = idx >> 6, c = idx & 63;
        tile[r][c] = src[(size_t)(r0 + r) * C + c0 + c];
    }
    __syncthreads();
#pragma unroll
    for (int j = 0; j < 16; ++j) {
        int idx = j * 256 + t;
        int c = idx >> 6, r = idx & 63;
        dst[(size_t)(c0 + c) * R + r0 + r] = f2bf(tile[r][c]);
    }
}

// ---------------------------------------------------------------------------
// bf16 MFMA GEMM, all-NT: C[M,N] = A[M,K(sA)] * B[N,K(sB)]^T
// BM = FM*32, BN = FN*32; 4 waves (2x2), wave tile (FM*16) x (FN*16).
// LDS: [row][32 k] bf16, 16B chunks XOR-swizzled: ck' = ck ^ ((row>>1)&3).
// EPI 0: fp32 store to Cf[M][N]
// EPI 1: bf16 store to Cb[row*sCb + col]
// EPI 2: g=sigmoid(acc+bias[col]); out = g*z + (1-g)*z_hat  (z fp32, z_hat bf16)
// ---------------------------------------------------------------------------
template <int FM, int FN, int EPI>
__global__ __launch_bounds__(256) void mfma_gemm_kernel(
    const u16* __restrict__ A, int sA,
    const u16* __restrict__ B, int sB,
    int M, int N, int K,
    float* __restrict__ Cf,
    u16* __restrict__ Cb, int sCb,
    const float* __restrict__ bias,
    const float* __restrict__ zf32,
    const u16* __restrict__ zhbf, int szh,
    float* __restrict__ outf) {
    constexpr int BM = FM * 32, BN = FN * 32;
    constexpr int NA = (BM * 4) / 256;  // 16B chunks per thread (A)
    constexpr int NB = (BN * 4) / 256;
    __shared__ __align__(16) u16 As[BM * 32];
    __shared__ __align__(16) u16 Bs[BN * 32];
    const int t = threadIdx.x;
    const int lane = t & 63;
    const int wid = t >> 6;
    const int wm = wid >> 1, wn = wid & 1;
    const int m0 = blockIdx.x * BM, n0 = blockIdx.y * BN;
    const int g = lane >> 4, lr = lane & 15;

    f32x4 acc[FM][FN];
#pragma unroll
    for (int i = 0; i < FM; ++i)
#pragma unroll
        for (int j = 0; j < FN; ++j) acc[i][j] = (f32x4){0.f, 0.f, 0.f, 0.f};

    short8v ra[NA], rb[NB];
#pragma unroll
    for (int j = 0; j < NA; ++j) {
        int c = j * 256 + t, row = c >> 2, ck = (c & 3) ^ ((row >> 1) & 3);
        ra[j] = *reinterpret_cast<const short8v*>(A + (size_t)(m0 + row) * sA + ck * 8);
    }
#pragma unroll
    for (int j = 0; j < NB; ++j) {
        int c = j * 256 + t, row = c >> 2, ck = (c & 3) ^ ((row >> 1) & 3);
        rb[j] = *reinterpret_cast<const short8v*>(B + (size_t)(n0 + row) * sB + ck * 8);
    }

    for (int k0 = 0; k0 < K; k0 += 32) {
        __syncthreads();
#pragma unroll
        for (int j = 0; j < NA; ++j)
            *reinterpret_cast<short8v*>(As + ((j * 256 + t) << 3)) = ra[j];
#pragma unroll
        for (int j = 0; j < NB; ++j)
            *reinterpret_cast<short8v*>(Bs + ((j * 256 + t) << 3)) = rb[j];
        __syncthreads();
        if (k0 + 32 < K) {  // prefetch next tile, overlapped with MFMA below
#pragma unroll
            for (int j = 0; j < NA; ++j) {
                int c = j * 256 + t, row = c >> 2, ck = (c & 3) ^ ((row >> 1) & 3);
                ra[j] = *reinterpret_cast<const short8v*>(A + (size_t)(m0 + row) * sA + k0 + 32 + ck * 8);
            }
#pragma unroll
            for (int j = 0; j < NB; ++j) {
                int c = j * 256 + t, row = c >> 2, ck = (c & 3) ^ ((row >> 1) & 3);
                rb[j] = *reinterpret_cast<const short8v*>(B + (size_t)(n0 + row) * sB + k0 + 32 + ck * 8);
            }
        }
        short8v af[FM], bfr[FN];
#pragma unroll
        for (int fm = 0; fm < FM; ++fm) {
            int row = wm * (FM * 16) + fm * 16 + lr;
            int ck = g ^ ((row >> 1) & 3);
            af[fm] = *reinterpret_cast<const short8v*>(As + row * 32 + ck * 8);
        }
#pragma unroll
        for (int fn = 0; fn < FN; ++fn) {
            int col = wn * (FN * 16) + fn * 16 + lr;
            int ck = g ^ ((col >> 1) & 3);
            bfr[fn] = *reinterpret_cast<const short8v*>(Bs + col * 32 + ck * 8);
        }
#pragma unroll
        for (int fm = 0; fm < FM; ++fm)
#pragma unroll
            for (int fn = 0; fn < FN; ++fn)
                acc[fm][fn] = __builtin_amdgcn_mfma_f32_16x16x32_bf16(
                    af[fm], bfr[fn], acc[fm][fn], 0, 0, 0);
    }

#pragma unroll
    for (int fm = 0; fm < FM; ++fm) {
#pragma unroll
        for (int fn = 0; fn < FN; ++fn) {
#pragma unroll
            for (int r = 0; r < 4; ++r) {
                int row = m0 + wm * (FM * 16) + fm * 16 + g * 4 + r;
                int col = n0 + wn * (FN * 16) + fn * 16 + lr;
                float v = acc[fm][fn][r];
                if (EPI == 0) {
                    Cf[(size_t)row * N + col] = v;
                } else if (EPI == 1) {
                    Cb[(size_t)row * sCb + col] = f2bf(v);
                } else {
                    float gs = 1.0f / (1.0f + __expf(-(v + bias[col])));
                    float zv = zf32[(size_t)row * N + col];
                    float zh = bf2f(zhbf[(size_t)row * szh + col]);
                    outf[(size_t)row * N + col] = gs * zv + (1.0f - gs) * zh;
                }
            }
        }
    }
}

// ---------------------------------------------------------------------------
// softmax over K=512 with cosine scaling; writes attn (fp32, d_out) + bf16 copy
// ---------------------------------------------------------------------------
__global__ __launch_bounds__(256) void softmax_kernel(const float* __restrict__ dots,
                                                      const float* __restrict__ zn,
                                                      const float* __restrict__ pn,
                                                      float* __restrict__ attn,
                                                      u16* __restrict__ attn_bf) {
    int m = blockIdx.x;
    int t = threadIdx.x;
    float zm = zn[m];
    float d0 = dots[(size_t)m * 512 + t];
    float d1 = dots[(size_t)m * 512 + t + 256];
    float v0 = d0 / fmaxf(zm * pn[t], EPS_COS);
    float v1 = d1 / fmaxf(zm * pn[t + 256], EPS_COS);
    float mx = fmaxf(v0, v1);
#pragma unroll
    for (int off = 32; off > 0; off >>= 1) mx = fmaxf(mx, __shfl_down(mx, off));
    __shared__ float red[8];
    int wave = t >> 6, lane = t & 63;
    if (lane == 0) red[wave] = mx;
    __syncthreads();
    if (t == 0) red[4] = fmaxf(fmaxf(red[0], red[1]), fmaxf(red[2], red[3]));
    __syncthreads();
    mx = red[4];
    float e0 = expf(v0 - mx), e1 = expf(v1 - mx);
    float s = e0 + e1;
#pragma unroll
    for (int off = 32; off > 0; off >>= 1) s += __shfl_down(s, off);
    if (lane == 0) red[wave] = s;
    __syncthreads();
    if (t == 0) red[5] = 1.0f / (red[0] + red[1] + red[2] + red[3]);
    __syncthreads();
    float r = red[5];
    float a0 = e0 * r, a1 = e1 * r;
    attn[(size_t)m * 512 + t] = a0;
    attn[(size_t)m * 512 + t + 256] = a1;
    attn_bf[(size_t)m * 512 + t] = f2bf(a0);
    attn_bf[(size_t)m * 512 + t + 256] = f2bf(a1);
}

// ---------------------------------------------------------------------------
// pooled[b,d] = mean_n z_fused[b,n,d]
// ---------------------------------------------------------------------------
__global__ __launch_bounds__(256) void pool_kernel(const float* __restrict__ zf,
                                                   float* __restrict__ pooled) {
    int idx = blockIdx.x * 256 + threadIdx.x;  // 32768
    int b = idx >> 10, d = idx & 1023;
    const float* p = zf + (size_t)b * 196 * 1024 + d;
    float s = 0.0f;
    for (int n = 0; n < 196; ++n) s += p[(size_t)n * 1024];
    pooled[idx] = s / 196.0f;
}

// ---------------------------------------------------------------------------
// h = pooled @ dec_w + dec_b : 392 blocks x 1024 thr; 64 cols/wave x 16
// batch-groups (2 batches each). Weight lines shared across waves via L1.
// ---------------------------------------------------------------------------
__global__ __launch_bounds__(1024) void dec_kernel(const float* __restrict__ pooled,
                                                   const float* __restrict__ dec_w,
                                                   const float* __restrict__ dec_b,
                                                   float* __restrict__ h) {
    int lane = threadIdx.x & 63;
    int bg = threadIdx.x >> 6;  // 0..15
    int c = blockIdx.x * 64 + lane;
    const float* p0 = pooled + (size_t)(bg * 2) * 1024;
    const float* p1 = p0 + 1024;
    const float* wp = dec_w + c;
    float acc0 = 0.f, acc1 = 0.f;
#pragma unroll 8
    for (int k = 0; k < 1024; ++k) {
        float wv = wp[(size_t)k * 25088];
        acc0 = fmaf(p0[k], wv, acc0);
        acc1 = fmaf(p1[k], wv, acc1);
    }
    float bb = dec_b[c];
    h[(size_t)(bg * 2) * 25088 + c] = acc0 + bb;
    h[(size_t)(bg * 2 + 1) * 25088 + c] = acc1 + bb;
}

// ---------------------------------------------------------------------------
// ct1_w [512][256][4][4] -> wt [p=4][tap=4][512][256]
// ---------------------------------------------------------------------------
__global__ __launch_bounds__(256) void wtrans_kernel(const float* __restrict__ wsrc,
                                                     float* __restrict__ wt) {
    int idx = blockIdx.x * 256 + threadIdx.x;
    int oc = idx & 255, ic = idx >> 8;
    float v[16];
#pragma unroll
    for (int i = 0; i < 16; ++i) v[i] = wsrc[(size_t)idx * 16 + i];
#pragma unroll
    for (int pp = 0; pp < 4; ++pp) {
        int py = pp >> 1, px = pp & 1;
#pragma unroll
        for (int tap = 0; tap < 4; ++tap) {
            int ty = tap >> 1, tx = tap & 1;
            int ky = (1 - py) + 2 * ty;
            int kx = (1 - px) + 2 * tx;
            wt[((size_t)(pp * 4 + tap) * 512 + ic) * 256 + oc] = v[ky * 4 + kx];
        }
    }
}

// ---------------------------------------------------------------------------
// ConvTranspose2d(512->256,k4,s2,p1)+bias+relu via parity classes
// ---------------------------------------------------------------------------
#define ICC 32
__global__ __launch_bounds__(128) void convt1_kernel(const float* __restrict__ h,
                                                     const float* __restrict__ wt,
                                                     const float* __restrict__ bias,
                                                     float* __restrict__ out) {
    const int oct = blockIdx.x;
    const int p = blockIdx.y;
    const int b = blockIdx.z;
    const int py = p >> 1, px = p & 1;
    const int t = threadIdx.x;
    const int og = t & 7;
    const int sg = t >> 3;
    const int sgy = sg >> 2, sgx = sg & 3;

    __shared__ float hs[ICC][100];
    __shared__ float ws[4][ICC][64];

    for (int l = t; l < ICC * 100; l += 128) ((float*)hs)[l] = 0.0f;

    float acc[4][8];
#pragma unroll
    for (int i = 0; i < 4; ++i)
#pragma unroll
        for (int j = 0; j < 8; ++j) acc[i][j] = 0.0f;

    const float* hb = h + (size_t)b * 25088;
    const int R0 = 2 * sgy + py;
    const int C0 = 2 * sgx + px;

    for (int ic0 = 0; ic0 < 512; ic0 += ICC) {
        __syncthreads();
        for (int l = t; l < ICC * 49; l += 128) {
            int i = l / 49, s = l - i * 49;
            int sy = s / 7, sx = s - sy * 7;
            hs[i][(sy + 1) * 9 + sx + 1] = hb[(size_t)(ic0 + i) * 49 + s];
        }
        for (int l = t; l < 4 * ICC * 64; l += 128) {
            int tap = l >> 11;
            int i = (l >> 6) & 31;
            int ol = l & 63;
            ws[tap][i][ol] =
                wt[((size_t)(p * 4 + tap) * 512 + ic0 + i) * 256 + oct * 64 + ol];
        }
        __syncthreads();
        for (int i = 0; i < ICC; ++i) {
            float hv[3][3];
#pragma unroll
            for (int ri = 0; ri < 3; ++ri)
#pragma unroll
                for (int ci = 0; ci < 3; ++ci)
                    hv[ri][ci] = hs[i][(R0 + ri) * 9 + (C0 + ci)];
#pragma unroll
            for (int tap = 0; tap < 4; ++tap) {
                int ty = tap >> 1, tx = tap & 1;
                float4 w0 = *reinterpret_cast<const float4*>(&ws[tap][i][og * 8]);
                float4 w1 = *reinterpret_cast<const float4*>(&ws[tap][i][og * 8 + 4]);
                float w[8] = {w0.x, w0.y, w0.z, w0.w, w1.x, w1.y, w1.z, w1.w};
#pragma unroll
                for (int dy = 0; dy < 2; ++dy)
#pragma unroll
                    for (int dx = 0; dx < 2; ++dx) {
                        float hvv = hv[dy - ty + 1][dx - tx + 1];
#pragma unroll
                        for (int j = 0; j < 8; ++j)
                            acc[dy * 2 + dx][j] = fmaf(hvv, w[j], acc[dy * 2 + dx][j]);
                    }
            }
        }
    }
#pragma unroll
    for (int dy = 0; dy < 2; ++dy) {
        int sy = 2 * sgy + dy;
        if (sy >= 7) continue;
        int oy = 2 * sy + py;
#pragma unroll
        for (int dx = 0; dx < 2; ++dx) {
            int sx = 2 * sgx + dx;
            if (sx >= 7) continue;
            int ox = 2 * sx + px;
#pragma unroll
            for (int j = 0; j < 8; ++j) {
                int oc = oct * 64 + og * 8 + j;
                float v = acc[dy * 2 + dx][j] + bias[oc];
                out[(((size_t)b * 256 + oc) * 14 + oy) * 14 + ox] = fmaxf(v, 0.0f);
            }
        }
    }
}

// ---------------------------------------------------------------------------
// ConvTranspose2d(256->3,k4,s2,p1)+bias
// ---------------------------------------------------------------------------
__global__ __launch_bounds__(256) void convt2_kernel(const float* __restrict__ h2,
                                                     const float* __restrict__ w,
                                                     const float* __restrict__ bias,
                                                     float* __restrict__ out) {
    int o = blockIdx.x * 256 + threadIdx.x;
    int ox = o % 28;
    int oy = (o / 28) % 28;
    int oc = (o / 784) % 3;
    int b = o / 2352;
    float acc = bias[oc];
    int ky0 = (oy + 1) & 1, kx0 = (ox + 1) & 1;
    const float* hbase = h2 + (size_t)b * 256 * 196;
#pragma unroll
    for (int tt = 0; tt < 4; ++tt) {
        int ky = ky0 + 2 * (tt >> 1);
        int kx = kx0 + 2 * (tt & 1);
        int iy = (oy + 1 - ky) >> 1;
        int ix = (ox + 1 - kx) >> 1;
        if ((unsigned)iy < 14u && (unsigned)ix < 14u) {
            const float* hp = hbase + iy * 14 + ix;
            const float* wp = w + oc * 16 + ky * 4 + kx;
            for (int ic = 0; ic < 256; ++ic)
                acc = fmaf(hp[(size_t)ic * 196], wp[ic * 48], acc);
        }
    }
    out[o] = acc;
}

// ---------------------------------------------------------------------------
extern "C" void kernel_launch(void* const* d_in, const int* in_sizes, int n_in,
                              void* d_out, int out_size, void* d_ws, size_t ws_size,
                              hipStream_t stream) {
    const float* z      = (const float*)d_in[0];  // [32,196,1024]
    const float* protos = (const float*)d_in[1];  // [512,1024]
    const float* gate_w = (const float*)d_in[2];  // [2048,1024]
    const float* gate_b = (const float*)d_in[3];  // [1024]
    const float* dec_w  = (const float*)d_in[4];  // [1024,25088]
    const float* dec_b  = (const float*)d_in[5];  // [25088]
    const float* ct1_w  = (const float*)d_in[6];  // [512,256,4,4]
    const float* ct1_b  = (const float*)d_in[7];  // [256]
    const float* ct2_w  = (const float*)d_in[8];  // [256,3,4,4]
    const float* ct2_b  = (const float*)d_in[9];  // [3]

    float* xout = (float*)d_out;   // x_recon 75264
    float* attn = xout + 75264;    // attn 3211264

    float* w = (float*)d_ws;
    float* pn        = w;                       // 512
    float* zn        = w + 512;                 // 6272
    float* pooled    = w + 6784;                // 32768
    float* hbuf      = w + 39552;               // 802816
    float* h2        = w + 842368;              // 1605632
    float* wt1       = w + 2448000;             // 2097152
    u16*   protos_bf = (u16*)(w + 4545152);     // 524288 u16
    u16*   protosT   = (u16*)(w + 4807296);     // 524288 u16
    u16*   gwT       = (u16*)(w + 5069440);     // 2097152 u16
    u16*   attn_bf   = (u16*)(w + 6118016);     // 3211264 u16
    u16*   Abig      = (u16*)(w + 7723648);     // 12845056 u16 [6272][2048]
    float* dots      = w + 14146176;            // 3211264 (dead after softmax)
    float* z_fused   = w + 14146176;            // 6422528 (overlays dots)

    // bf16 operand prep
    cvt_bf_kernel<<<3136, 256, 0, stream>>>(z, Abig, 1024, 2048, 6422528);
    cvt_bf_kernel<<<256, 256, 0, stream>>>(protos, protos_bf, 1024, 1024, 524288);
    transpose_cvt_kernel<<<dim3(16, 8), 256, 0, stream>>>(protos, protosT, 512, 1024);
    transpose_cvt_kernel<<<dim3(16, 32), 256, 0, stream>>>(gate_w, gwT, 2048, 1024);
    wtrans_kernel<<<512, 256, 0, stream>>>(ct1_w, wt1);
    // norms
    norm_rows_kernel<<<512, 256, 0, stream>>>(protos, pn);
    norm_rows_kernel<<<6272, 256, 0, stream>>>(z, zn);
    // dots = z @ protos^T  (M=6272, N=512, K=1024)
    mfma_gemm_kernel<2, 4, 0><<<dim3(98, 4), 256, 0, stream>>>(
        Abig, 2048, protos_bf, 1024, 6272, 512, 1024,
        dots, nullptr, 0, nullptr, nullptr, nullptr, 0, nullptr);
    // softmax -> attn (fp32 out) + attn_bf
    softmax_kernel<<<6272, 256, 0, stream>>>(dots, zn, pn, attn, attn_bf);
    // z_hat = attn @ protos (M=6272, N=1024, K=512) -> bf16 into Abig right half
    mfma_gemm_kernel<4, 4, 1><<<dim3(49, 8), 256, 0, stream>>>(
        attn_bf, 512, protosT, 512, 6272, 1024, 512,
        nullptr, Abig + 1024, 2048, nullptr, nullptr, nullptr, 0, nullptr);
    // gate GEMM (K=2048) + sigmoid blend -> z_fused
    mfma_gemm_kernel<4, 4, 2><<<dim3(49, 8), 256, 0, stream>>>(
        Abig, 2048, gwT, 2048, 6272, 1024, 2048,
        nullptr, nullptr, 0, gate_b, z, Abig + 1024, 2048, z_fused);
    // pool -> decoder -> convT1 -> convT2
    pool_kernel<<<128, 256, 0, stream>>>(z_fused, pooled);
    dec_kernel<<<392, 1024, 0, stream>>>(pooled, dec_w, dec_b, hbuf);
    convt1_kernel<<<dim3(4, 4, 32), 128, 0, stream>>>(hbuf, wt1, ct1_b, h2);
    convt2_kernel<<<294, 256, 0, stream>>>(h2, ct2_w, ct2_b, xout);
}

// Round 4
// 436.132 us; speedup vs baseline: 3.0775x; 1.6603x over previous
//
#include <hip/hip_runtime.h>
#include <cstdint>
#include <cstddef>
#include <cmath>

#define EPS_COS 1e-8f

typedef unsigned short u16;
typedef __attribute__((ext_vector_type(8))) short short8v;
typedef __attribute__((ext_vector_type(4))) float f32x4;

__device__ __forceinline__ u16 f2bf(float x) {
    unsigned int u = __float_as_uint(x);
    return (u16)((u + 0x7FFFu + ((u >> 16) & 1u)) >> 16);  // RNE
}
__device__ __forceinline__ float bf2f(u16 h) {
    return __uint_as_float(((unsigned int)h) << 16);
}

// ---------------------------------------------------------------------------
// row L2 norms (C fixed = 1024)
// ---------------------------------------------------------------------------
__global__ __launch_bounds__(256) void norm_rows_kernel(const float* __restrict__ X,
                                                        float* __restrict__ out) {
    int r = blockIdx.x;
    int t = threadIdx.x;
    const float4 v = *reinterpret_cast<const float4*>(&X[(size_t)r * 1024 + t * 4]);
    float ss = v.x * v.x + v.y * v.y + v.z * v.z + v.w * v.w;
#pragma unroll
    for (int off = 32; off > 0; off >>= 1) ss += __shfl_down(ss, off);
    __shared__ float red[4];
    int wave = t >> 6, lane = t & 63;
    if (lane == 0) red[wave] = ss;
    __syncthreads();
    if (t == 0) out[r] = sqrtf(red[0] + red[1] + red[2] + red[3]);
}

// ---------------------------------------------------------------------------
// fp32 -> bf16 copy (row-strided dst), 8 elems/thread
// ---------------------------------------------------------------------------
__global__ __launch_bounds__(256) void cvt_bf_kernel(const float* __restrict__ src,
                                                     u16* __restrict__ dst,
                                                     int srcW, int dstStride, int nElem) {
    int idx = blockIdx.x * 256 + threadIdx.x;
    int e = idx * 8;
    if (e >= nElem) return;
    float4 v0 = *reinterpret_cast<const float4*>(src + e);
    float4 v1 = *reinterpret_cast<const float4*>(src + e + 4);
    int row = e / srcW, col = e - row * srcW;
    u16* d = dst + (size_t)row * dstStride + col;
    short8v o;
    o[0] = f2bf(v0.x); o[1] = f2bf(v0.y); o[2] = f2bf(v0.z); o[3] = f2bf(v0.w);
    o[4] = f2bf(v1.x); o[5] = f2bf(v1.y); o[6] = f2bf(v1.z); o[7] = f2bf(v1.w);
    *reinterpret_cast<short8v*>(d) = o;
}

// ---------------------------------------------------------------------------
// transpose + cvt: src [R][C] f32 -> dst [C][R] bf16 (64x64 LDS tiles, +1 pad)
// ---------------------------------------------------------------------------
__global__ __launch_bounds__(256) void transpose_cvt_kernel(const float* __restrict__ src,
                                                            u16* __restrict__ dst,
                                                            int R, int C) {
    __shared__ float tile[64][65];
    int c0 = blockIdx.x * 64, r0 = blockIdx.y * 64;
    int t = threadIdx.x;
#pragma unroll
    for (int j = 0; j < 16; ++j) {
        int idx = j * 256 + t;
        int r = idx >> 6, c = idx & 63;
        tile[r][c] = src[(size_t)(r0 + r) * C + c0 + c];
    }
    __syncthreads();
#pragma unroll
    for (int j = 0; j < 16; ++j) {
        int idx = j * 256 + t;
        int c = idx >> 6, r = idx & 63;
        dst[(size_t)(c0 + c) * R + r0 + r] = f2bf(tile[r][c]);
    }
}

// ---------------------------------------------------------------------------
// bf16 MFMA GEMM, all-NT: C[M,N] = A[M,K(sA)] * B[N,K(sB)]^T
// blockIdx.z selects a (A,B) pair via zsA/zsB element strides (grouped GEMM).
// BM = FM*32, BN = FN*32; 4 waves (2x2), wave tile (FM*16) x (FN*16).
// LDS: [row][32 k] bf16, 16B chunks XOR-swizzled: ck' = ck ^ ((row>>1)&3).
// EPI 0: fp32 store to Cf[M][N]
// EPI 1: bf16 store to Cb[row*sCb + col]
// EPI 2: g=sigmoid(acc+bias[col]); outf = g*z + (1-g)*z_hat (z fp32, z_hat bf16)
// EPI 3: relu(acc+bias[col]) -> h2c[((b*4+z)*49+s)*256 + col], row=b*49+s<1568
// ---------------------------------------------------------------------------
template <int FM, int FN, int EPI>
__global__ __launch_bounds__(256) void mfma_gemm_kernel(
    const u16* __restrict__ A, int sA, size_t zsA,
    const u16* __restrict__ B, int sB, size_t zsB,
    int M, int N, int K,
    float* __restrict__ Cf,
    u16* __restrict__ Cb, int sCb,
    const float* __restrict__ bias,
    const float* __restrict__ zf32,
    const u16* __restrict__ zhbf, int szh,
    float* __restrict__ outf) {
    constexpr int BM = FM * 32, BN = FN * 32;
    constexpr int NA = (BM * 4) / 256;  // 16B chunks per thread (A)
    constexpr int NB = (BN * 4) / 256;
    __shared__ __align__(16) u16 As[BM * 32];
    __shared__ __align__(16) u16 Bs[BN * 32];
    A += (size_t)blockIdx.z * zsA;
    B += (size_t)blockIdx.z * zsB;
    const int t = threadIdx.x;
    const int lane = t & 63;
    const int wid = t >> 6;
    const int wm = wid >> 1, wn = wid & 1;
    const int m0 = blockIdx.x * BM, n0 = blockIdx.y * BN;
    const int g = lane >> 4, lr = lane & 15;

    f32x4 acc[FM][FN];
#pragma unroll
    for (int i = 0; i < FM; ++i)
#pragma unroll
        for (int j = 0; j < FN; ++j) acc[i][j] = (f32x4){0.f, 0.f, 0.f, 0.f};

    short8v ra[NA], rb[NB];
#pragma unroll
    for (int j = 0; j < NA; ++j) {
        int c = j * 256 + t, row = c >> 2, ck = (c & 3) ^ ((row >> 1) & 3);
        ra[j] = *reinterpret_cast<const short8v*>(A + (size_t)(m0 + row) * sA + ck * 8);
    }
#pragma unroll
    for (int j = 0; j < NB; ++j) {
        int c = j * 256 + t, row = c >> 2, ck = (c & 3) ^ ((row >> 1) & 3);
        rb[j] = *reinterpret_cast<const short8v*>(B + (size_t)(n0 + row) * sB + ck * 8);
    }

    for (int k0 = 0; k0 < K; k0 += 32) {
        __syncthreads();
#pragma unroll
        for (int j = 0; j < NA; ++j)
            *reinterpret_cast<short8v*>(As + ((j * 256 + t) << 3)) = ra[j];
#pragma unroll
        for (int j = 0; j < NB; ++j)
            *reinterpret_cast<short8v*>(Bs + ((j * 256 + t) << 3)) = rb[j];
        __syncthreads();
        if (k0 + 32 < K) {  // prefetch next tile, overlapped with MFMA below
#pragma unroll
            for (int j = 0; j < NA; ++j) {
                int c = j * 256 + t, row = c >> 2, ck = (c & 3) ^ ((row >> 1) & 3);
                ra[j] = *reinterpret_cast<const short8v*>(A + (size_t)(m0 + row) * sA + k0 + 32 + ck * 8);
            }
#pragma unroll
            for (int j = 0; j < NB; ++j) {
                int c = j * 256 + t, row = c >> 2, ck = (c & 3) ^ ((row >> 1) & 3);
                rb[j] = *reinterpret_cast<const short8v*>(B + (size_t)(n0 + row) * sB + k0 + 32 + ck * 8);
            }
        }
        short8v af[FM], bfr[FN];
#pragma unroll
        for (int fm = 0; fm < FM; ++fm) {
            int row = wm * (FM * 16) + fm * 16 + lr;
            int ck = g ^ ((row >> 1) & 3);
            af[fm] = *reinterpret_cast<const short8v*>(As + row * 32 + ck * 8);
        }
#pragma unroll
        for (int fn = 0; fn < FN; ++fn) {
            int col = wn * (FN * 16) + fn * 16 + lr;
            int ck = g ^ ((col >> 1) & 3);
            bfr[fn] = *reinterpret_cast<const short8v*>(Bs + col * 32 + ck * 8);
        }
#pragma unroll
        for (int fm = 0; fm < FM; ++fm)
#pragma unroll
            for (int fn = 0; fn < FN; ++fn)
                acc[fm][fn] = __builtin_amdgcn_mfma_f32_16x16x32_bf16(
                    af[fm], bfr[fn], acc[fm][fn], 0, 0, 0);
    }

#pragma unroll
    for (int fm = 0; fm < FM; ++fm) {
#pragma unroll
        for (int fn = 0; fn < FN; ++fn) {
#pragma unroll
            for (int r = 0; r < 4; ++r) {
                int row = m0 + wm * (FM * 16) + fm * 16 + g * 4 + r;
                int col = n0 + wn * (FN * 16) + fn * 16 + lr;
                float v = acc[fm][fn][r];
                if (EPI == 0) {
                    Cf[(size_t)row * N + col] = v;
                } else if (EPI == 1) {
                    Cb[(size_t)row * sCb + col] = f2bf(v);
                } else if (EPI == 2) {
                    float gs = 1.0f / (1.0f + __expf(-(v + bias[col])));
                    float zv = zf32[(size_t)row * N + col];
                    float zh = bf2f(zhbf[(size_t)row * szh + col]);
                    outf[(size_t)row * N + col] = gs * zv + (1.0f - gs) * zh;
                } else {  // EPI == 3: convT1 epilogue
                    if (row < 1568) {
                        float vv = fmaxf(v + bias[col], 0.0f);
                        int bb = row / 49, ss = row - bb * 49;
                        outf[(((size_t)bb * 4 + blockIdx.z) * 49 + ss) * 256 + col] = vv;
                    }
                }
            }
        }
    }
}

// ---------------------------------------------------------------------------
// softmax over K=512 with cosine scaling; writes attn (fp32, d_out) + bf16 copy
// ---------------------------------------------------------------------------
__global__ __launch_bounds__(256) void softmax_kernel(const float* __restrict__ dots,
                                                      const float* __restrict__ zn,
                                                      const float* __restrict__ pn,
                                                      float* __restrict__ attn,
                                                      u16* __restrict__ attn_bf) {
    int m = blockIdx.x;
    int t = threadIdx.x;
    float zm = zn[m];
    float d0 = dots[(size_t)m * 512 + t];
    float d1 = dots[(size_t)m * 512 + t + 256];
    float v0 = d0 / fmaxf(zm * pn[t], EPS_COS);
    float v1 = d1 / fmaxf(zm * pn[t + 256], EPS_COS);
    float mx = fmaxf(v0, v1);
#pragma unroll
    for (int off = 32; off > 0; off >>= 1) mx = fmaxf(mx, __shfl_down(mx, off));
    __shared__ float red[8];
    int wave = t >> 6, lane = t & 63;
    if (lane == 0) red[wave] = mx;
    __syncthreads();
    if (t == 0) red[4] = fmaxf(fmaxf(red[0], red[1]), fmaxf(red[2], red[3]));
    __syncthreads();
    mx = red[4];
    float e0 = expf(v0 - mx), e1 = expf(v1 - mx);
    float s = e0 + e1;
#pragma unroll
    for (int off = 32; off > 0; off >>= 1) s += __shfl_down(s, off);
    if (lane == 0) red[wave] = s;
    __syncthreads();
    if (t == 0) red[5] = 1.0f / (red[0] + red[1] + red[2] + red[3]);
    __syncthreads();
    float r = red[5];
    float a0 = e0 * r, a1 = e1 * r;
    attn[(size_t)m * 512 + t] = a0;
    attn[(size_t)m * 512 + t + 256] = a1;
    attn_bf[(size_t)m * 512 + t] = f2bf(a0);
    attn_bf[(size_t)m * 512 + t + 256] = f2bf(a1);
}

// ---------------------------------------------------------------------------
// pooled[b,d] = mean_n z_fused[b,n,d]
// ---------------------------------------------------------------------------
__global__ __launch_bounds__(256) void pool_kernel(const float* __restrict__ zf,
                                                   float* __restrict__ pooled) {
    int idx = blockIdx.x * 256 + threadIdx.x;  // 32768
    int b = idx >> 10, d = idx & 1023;
    const float* p = zf + (size_t)b * 196 * 1024 + d;
    float s = 0.0f;
    for (int n = 0; n < 196; ++n) s += p[(size_t)n * 1024];
    pooled[idx] = s / 196.0f;
}

// ---------------------------------------------------------------------------
// zero hp (padded bf16 h buffer [32][512][81])
// ---------------------------------------------------------------------------
__global__ __launch_bounds__(256) void hp_zero_kernel(u16* __restrict__ hp) {
    int i = blockIdx.x * 256 + threadIdx.x;  // < 165888 short8 groups
    short8v zv = {0, 0, 0, 0, 0, 0, 0, 0};
    *reinterpret_cast<short8v*>(hp + (size_t)i * 8) = zv;
}

// ---------------------------------------------------------------------------
// h = pooled @ dec_w + dec_b, written bf16 into padded hp[b][ic][9][9] interior
// ---------------------------------------------------------------------------
__global__ __launch_bounds__(1024) void dec_kernel(const float* __restrict__ pooled,
                                                   const float* __restrict__ dec_w,
                                                   const float* __restrict__ dec_b,
                                                   u16* __restrict__ hp) {
    int lane = threadIdx.x & 63;
    int bg = threadIdx.x >> 6;  // 0..15
    int c = blockIdx.x * 64 + lane;
    const float* p0 = pooled + (size_t)(bg * 2) * 1024;
    const float* p1 = p0 + 1024;
    const float* wp = dec_w + c;
    float acc0 = 0.f, acc1 = 0.f;
#pragma unroll 8
    for (int k = 0; k < 1024; ++k) {
        float wv = wp[(size_t)k * 25088];
        acc0 = fmaf(p0[k], wv, acc0);
        acc1 = fmaf(p1[k], wv, acc1);
    }
    float bb = dec_b[c];
    int ic = c / 49, s = c - ic * 49;
    int sy = s / 7, sx = s - sy * 7;
    int off = (sy + 1) * 9 + sx + 1;
    hp[((size_t)(bg * 2) * 512 + ic) * 81 + off] = f2bf(acc0 + bb);
    hp[((size_t)(bg * 2 + 1) * 512 + ic) * 81 + off] = f2bf(acc1 + bb);
}

// ---------------------------------------------------------------------------
// im2col for convT1 parity classes: A[p][row=b*49+s][k=ic*4+tap] bf16
// tap=ty*2+tx reads hp[b][ic][sy+py-ty+1][sx+px-tx+1]; rows>=1568 zeroed
// ---------------------------------------------------------------------------
__global__ __launch_bounds__(256) void im2col_kernel(const u16* __restrict__ hp,
                                                     u16* __restrict__ A) {
    int idx = blockIdx.x * 256 + threadIdx.x;  // < 1,638,400
    int k8 = idx & 255;                        // 8 cols = 2 ic x 4 taps
    int pr = idx >> 8;
    int p = pr / 1600;
    int row = pr - p * 1600;
    short8v o = {0, 0, 0, 0, 0, 0, 0, 0};
    if (row < 1568) {
        int b = row / 49, s = row - b * 49;
        int sy = s / 7, sx = s - sy * 7;
        int r0 = sy + (p >> 1) + 1;
        int c0 = sx + (p & 1) + 1;
        int ic0 = k8 * 2;
        const u16* hb = hp + ((size_t)b * 512 + ic0) * 81;
#pragma unroll
        for (int j = 0; j < 2; ++j) {
            o[j * 4 + 0] = hb[r0 * 9 + c0];
            o[j * 4 + 1] = hb[r0 * 9 + c0 - 1];
            o[j * 4 + 2] = hb[(r0 - 1) * 9 + c0];
            o[j * 4 + 3] = hb[(r0 - 1) * 9 + c0 - 1];
            hb += 81;
        }
    }
    *reinterpret_cast<short8v*>(A + (size_t)idx * 8) = o;
}

// ---------------------------------------------------------------------------
// ct1_w [512][256][4][4] -> wt1bf [p=4][oc=256][k=ic*4+tap] bf16
// ---------------------------------------------------------------------------
__global__ __launch_bounds__(256) void wtrans_kernel(const float* __restrict__ wsrc,
                                                     u16* __restrict__ wt) {
    int idx = blockIdx.x * 256 + threadIdx.x;  // ic*256+oc
    int oc = idx & 255, ic = idx >> 8;
    float v[16];
#pragma unroll
    for (int i = 0; i < 16; ++i) v[i] = wsrc[(size_t)idx * 16 + i];
#pragma unroll
    for (int pp = 0; pp < 4; ++pp) {
        int py = pp >> 1, px = pp & 1;
#pragma unroll
        for (int tap = 0; tap < 4; ++tap) {
            int ty = tap >> 1, tx = tap & 1;
            int ky = (1 - py) + 2 * ty;
            int kx = (1 - px) + 2 * tx;
            wt[((size_t)(pp * 256 + oc)) * 2048 + ic * 4 + tap] = f2bf(v[ky * 4 + kx]);
        }
    }
}

// ---------------------------------------------------------------------------
// ct2_w [256][3][4][4] -> w2t [oc=3][ky=4][kx=4][ic=256] (ic-contiguous fp32)
// ---------------------------------------------------------------------------
__global__ __launch_bounds__(256) void w2trans_kernel(const float* __restrict__ w,
                                                      float* __restrict__ w2t) {
    int idx = blockIdx.x * 256 + threadIdx.x;  // < 12288
    int ic = idx & 255;
    int r = idx >> 8;  // oc*16 + ky*4 + kx
    int kx = r & 3, ky = (r >> 2) & 3, oc = r >> 4;
    w2t[idx] = w[((size_t)ic * 3 + oc) * 16 + ky * 4 + kx];
}

// ---------------------------------------------------------------------------
// ConvTranspose2d(256->3,k4,s2,p1)+bias from h2c [b][p][49][ic=256] fp32
// ---------------------------------------------------------------------------
__global__ __launch_bounds__(256) void convt2_kernel(const float* __restrict__ h2c,
                                                     const float* __restrict__ w2t,
                                                     const float* __restrict__ bias,
                                                     float* __restrict__ out) {
    int o = blockIdx.x * 256 + threadIdx.x;  // < 75264
    int ox = o % 28;
    int oy = (o / 28) % 28;
    int oc = (o / 784) % 3;
    int b = o / 2352;
    int by = (oy + 1) >> 1, bx = (ox + 1) >> 1;
    float acc = bias[oc];
#pragma unroll
    for (int ty = 0; ty < 2; ++ty) {
        int iy = by - ty;
        if ((unsigned)iy >= 14u) continue;
#pragma unroll
        for (int tx = 0; tx < 2; ++tx) {
            int ix = bx - tx;
            if ((unsigned)ix >= 14u) continue;
            int p = (iy & 1) * 2 + (ix & 1);
            int sy = iy >> 1, sx = ix >> 1;
            int ky = oy + 1 - 2 * iy, kx = ox + 1 - 2 * ix;
            const float* hb = h2c + (((size_t)b * 4 + p) * 49 + sy * 7 + sx) * 256;
            const float* wb = w2t + ((oc * 4 + ky) * 4 + kx) * 256;
            for (int i = 0; i < 256; i += 4) {
                float4 h4 = *reinterpret_cast<const float4*>(hb + i);
                float4 w4 = *reinterpret_cast<const float4*>(wb + i);
                acc = fmaf(h4.x, w4.x, acc);
                acc = fmaf(h4.y, w4.y, acc);
                acc = fmaf(h4.z, w4.z, acc);
                acc = fmaf(h4.w, w4.w, acc);
            }
        }
    }
    out[o] = acc;
}

// ---------------------------------------------------------------------------
extern "C" void kernel_launch(void* const* d_in, const int* in_sizes, int n_in,
                              void* d_out, int out_size, void* d_ws, size_t ws_size,
                              hipStream_t stream) {
    const float* z      = (const float*)d_in[0];  // [32,196,1024]
    const float* protos = (const float*)d_in[1];  // [512,1024]
    const float* gate_w = (const float*)d_in[2];  // [2048,1024]
    const float* gate_b = (const float*)d_in[3];  // [1024]
    const float* dec_w  = (const float*)d_in[4];  // [1024,25088]
    const float* dec_b  = (const float*)d_in[5];  // [25088]
    const float* ct1_w  = (const float*)d_in[6];  // [512,256,4,4]
    const float* ct1_b  = (const float*)d_in[7];  // [256]
    const float* ct2_w  = (const float*)d_in[8];  // [256,3,4,4]
    const float* ct2_b  = (const float*)d_in[9];  // [3]

    float* xout = (float*)d_out;   // x_recon 75264
    float* attn = xout + 75264;    // attn 3211264

    float* w = (float*)d_ws;
    float* pn        = w;                       // 512
    float* zn        = w + 512;                 // 6272
    float* pooled    = w + 6784;                // 32768
    float* w2t       = w + 39552;               // 12288
    u16*   wt1bf     = (u16*)(w + 51840);       // 2,097,152 u16 -> ends 1,100,416
    u16*   protos_bf = (u16*)(w + 1100416);     // 524288 u16
    u16*   protosT   = (u16*)(w + 1362560);     // 524288 u16
    u16*   gwT       = (u16*)(w + 1624704);     // 2,097,152 u16 -> ends 2,673,280
    u16*   attn_bf   = (u16*)(w + 2673280);     // 3,211,264 u16
    u16*   Abig      = (u16*)(w + 4278912);     // [6272][2048] u16 -> ends 10,701,440
    u16*   A_cls     = (u16*)(w + 2673280);     // overlay attn_bf+Abig (dead by im2col)
    float* dots      = w + 10701440;            // 3,211,264
    float* z_fused   = w + 10701440;            // overlays dots (dead after softmax);
                                                //   spans .. 17,123,968
    float* h2c       = w + 11364992;            // overlays z_fused tail (dead after pool)
    u16*   hp        = (u16*)(w + 17123968);    // NON-overlapping (fix: zero border was
                                                //   being destroyed by z_fused write)
                                                //   663,552 floats -> ends 17,787,520 (71.2MB)

    // operand prep
    hp_zero_kernel<<<648, 256, 0, stream>>>(hp);
    cvt_bf_kernel<<<3136, 256, 0, stream>>>(z, Abig, 1024, 2048, 6422528);
    cvt_bf_kernel<<<256, 256, 0, stream>>>(protos, protos_bf, 1024, 1024, 524288);
    transpose_cvt_kernel<<<dim3(16, 8), 256, 0, stream>>>(protos, protosT, 512, 1024);
    transpose_cvt_kernel<<<dim3(16, 32), 256, 0, stream>>>(gate_w, gwT, 2048, 1024);
    wtrans_kernel<<<512, 256, 0, stream>>>(ct1_w, wt1bf);
    w2trans_kernel<<<48, 256, 0, stream>>>(ct2_w, w2t);
    // norms
    norm_rows_kernel<<<512, 256, 0, stream>>>(protos, pn);
    norm_rows_kernel<<<6272, 256, 0, stream>>>(z, zn);
    // dots = z @ protos^T  (M=6272, N=512, K=1024)
    mfma_gemm_kernel<2, 4, 0><<<dim3(98, 4), 256, 0, stream>>>(
        Abig, 2048, 0, protos_bf, 1024, 0, 6272, 512, 1024,
        dots, nullptr, 0, nullptr, nullptr, nullptr, 0, nullptr);
    // softmax -> attn (fp32 out) + attn_bf
    softmax_kernel<<<6272, 256, 0, stream>>>(dots, zn, pn, attn, attn_bf);
    // z_hat = attn @ protos (M=6272, N=1024, K=512) -> bf16 into Abig right half
    mfma_gemm_kernel<4, 4, 1><<<dim3(49, 8), 256, 0, stream>>>(
        attn_bf, 512, 0, protosT, 512, 0, 6272, 1024, 512,
        nullptr, Abig + 1024, 2048, nullptr, nullptr, nullptr, 0, nullptr);
    // gate GEMM (K=2048) + sigmoid blend -> z_fused
    mfma_gemm_kernel<4, 4, 2><<<dim3(49, 8), 256, 0, stream>>>(
        Abig, 2048, 0, gwT, 2048, 0, 6272, 1024, 2048,
        nullptr, nullptr, 0, gate_b, z, Abig + 1024, 2048, z_fused);
    // pool -> decoder (writes padded bf16 hp)
    pool_kernel<<<128, 256, 0, stream>>>(z_fused, pooled);
    dec_kernel<<<392, 1024, 0, stream>>>(pooled, dec_w, dec_b, hp);
    // convT1 as grouped MFMA GEMM: im2col then 4-class GEMM + bias/relu epilogue
    im2col_kernel<<<6400, 256, 0, stream>>>(hp, A_cls);
    mfma_gemm_kernel<2, 2, 3><<<dim3(25, 4, 4), 256, 0, stream>>>(
        A_cls, 2048, (size_t)1600 * 2048, wt1bf, 2048, (size_t)256 * 2048,
        1600, 256, 2048, nullptr, nullptr, 0, ct1_b, nullptr, nullptr, 0, h2c);
    // convT2 -> x_recon
    convt2_kernel<<<294, 256, 0, stream>>>(h2c, w2t, ct2_b, xout);
}

// Round 5
// 300.361 us; speedup vs baseline: 4.4686x; 1.4520x over previous
//
#include <hip/hip_runtime.h>
#include <cstdint>
#include <cstddef>
#include <cmath>

#define EPS_COS 1e-8f

typedef unsigned short u16;
typedef __attribute__((ext_vector_type(8))) short short8v;
typedef __attribute__((ext_vector_type(4))) float f32x4;

__device__ __forceinline__ u16 f2bf(float x) {
    unsigned int u = __float_as_uint(x);
    return (u16)((u + 0x7FFFu + ((u >> 16) & 1u)) >> 16);  // RNE
}
__device__ __forceinline__ float bf2f(u16 h) {
    return __uint_as_float(((unsigned int)h) << 16);
}

// ---------------------------------------------------------------------------
// row L2 norms (C fixed = 1024)
// ---------------------------------------------------------------------------
__global__ __launch_bounds__(256) void norm_rows_kernel(const float* __restrict__ X,
                                                        float* __restrict__ out) {
    int r = blockIdx.x;
    int t = threadIdx.x;
    const float4 v = *reinterpret_cast<const float4*>(&X[(size_t)r * 1024 + t * 4]);
    float ss = v.x * v.x + v.y * v.y + v.z * v.z + v.w * v.w;
#pragma unroll
    for (int off = 32; off > 0; off >>= 1) ss += __shfl_down(ss, off);
    __shared__ float red[4];
    int wave = t >> 6, lane = t & 63;
    if (lane == 0) red[wave] = ss;
    __syncthreads();
    if (t == 0) out[r] = sqrtf(red[0] + red[1] + red[2] + red[3]);
}

// ---------------------------------------------------------------------------
// fp32 -> bf16 copy (row-strided dst), 8 elems/thread
// ---------------------------------------------------------------------------
__global__ __launch_bounds__(256) void cvt_bf_kernel(const float* __restrict__ src,
                                                     u16* __restrict__ dst,
                                                     int srcW, int dstStride, int nElem) {
    int idx = blockIdx.x * 256 + threadIdx.x;
    int e = idx * 8;
    if (e >= nElem) return;
    float4 v0 = *reinterpret_cast<const float4*>(src + e);
    float4 v1 = *reinterpret_cast<const float4*>(src + e + 4);
    int row = e / srcW, col = e - row * srcW;
    u16* d = dst + (size_t)row * dstStride + col;
    short8v o;
    o[0] = f2bf(v0.x); o[1] = f2bf(v0.y); o[2] = f2bf(v0.z); o[3] = f2bf(v0.w);
    o[4] = f2bf(v1.x); o[5] = f2bf(v1.y); o[6] = f2bf(v1.z); o[7] = f2bf(v1.w);
    *reinterpret_cast<short8v*>(d) = o;
}

// ---------------------------------------------------------------------------
// transpose + cvt: src [R][C] f32 -> dst [C][R] bf16 (64x64 LDS tiles, +1 pad)
// ---------------------------------------------------------------------------
__global__ __launch_bounds__(256) void transpose_cvt_kernel(const float* __restrict__ src,
                                                            u16* __restrict__ dst,
                                                            int R, int C) {
    __shared__ float tile[64][65];
    int c0 = blockIdx.x * 64, r0 = blockIdx.y * 64;
    int t = threadIdx.x;
#pragma unroll
    for (int j = 0; j < 16; ++j) {
        int idx = j * 256 + t;
        int r = idx >> 6, c = idx & 63;
        tile[r][c] = src[(size_t)(r0 + r) * C + c0 + c];
    }
    __syncthreads();
#pragma unroll
    for (int j = 0; j < 16; ++j) {
        int idx = j * 256 + t;
        int c = idx >> 6, r = idx & 63;
        dst[(size_t)(c0 + c) * R + r0 + r] = f2bf(tile[r][c]);
    }
}

// ---------------------------------------------------------------------------
// bf16 MFMA GEMM, all-NT: C[M,N] = A[M,K(sA)] * B[N,K(sB)]^T
// blockIdx.z selects a (A,B) pair via zsA/zsB element strides (grouped GEMM).
// BM = FM*32, BN = FN*32; 4 waves (2x2), wave tile (FM*16) x (FN*16).
// LDS: [row][32 k] bf16, 16B chunks XOR-swizzled: ck' = ck ^ ((row>>1)&3).
// EPI 0: fp32 store to Cf[M][N]
// EPI 1: bf16 store to Cb[row*sCb + col]
// EPI 2: g=sigmoid(acc+bias[col]); outf = g*z + (1-g)*z_hat (z fp32, z_hat bf16)
// EPI 3: relu(acc+bias[col]) -> h2c[((b*4+z)*49+s)*256 + col], row=b*49+s<1568
// ---------------------------------------------------------------------------
template <int FM, int FN, int EPI>
__global__ __launch_bounds__(256) void mfma_gemm_kernel(
    const u16* __restrict__ A, int sA, size_t zsA,
    const u16* __restrict__ B, int sB, size_t zsB,
    int M, int N, int K,
    float* __restrict__ Cf,
    u16* __restrict__ Cb, int sCb,
    const float* __restrict__ bias,
    const float* __restrict__ zf32,
    const u16* __restrict__ zhbf, int szh,
    float* __restrict__ outf) {
    constexpr int BM = FM * 32, BN = FN * 32;
    constexpr int NA = (BM * 4) / 256;  // 16B chunks per thread (A)
    constexpr int NB = (BN * 4) / 256;
    __shared__ __align__(16) u16 As[BM * 32];
    __shared__ __align__(16) u16 Bs[BN * 32];
    A += (size_t)blockIdx.z * zsA;
    B += (size_t)blockIdx.z * zsB;
    const int t = threadIdx.x;
    const int lane = t & 63;
    const int wid = t >> 6;
    const int wm = wid >> 1, wn = wid & 1;
    const int m0 = blockIdx.x * BM, n0 = blockIdx.y * BN;
    const int g = lane >> 4, lr = lane & 15;

    f32x4 acc[FM][FN];
#pragma unroll
    for (int i = 0; i < FM; ++i)
#pragma unroll
        for (int j = 0; j < FN; ++j) acc[i][j] = (f32x4){0.f, 0.f, 0.f, 0.f};

    short8v ra[NA], rb[NB];
#pragma unroll
    for (int j = 0; j < NA; ++j) {
        int c = j * 256 + t, row = c >> 2, ck = (c & 3) ^ ((row >> 1) & 3);
        ra[j] = *reinterpret_cast<const short8v*>(A + (size_t)(m0 + row) * sA + ck * 8);
    }
#pragma unroll
    for (int j = 0; j < NB; ++j) {
        int c = j * 256 + t, row = c >> 2, ck = (c & 3) ^ ((row >> 1) & 3);
        rb[j] = *reinterpret_cast<const short8v*>(B + (size_t)(n0 + row) * sB + ck * 8);
    }

    for (int k0 = 0; k0 < K; k0 += 32) {
        __syncthreads();
#pragma unroll
        for (int j = 0; j < NA; ++j)
            *reinterpret_cast<short8v*>(As + ((j * 256 + t) << 3)) = ra[j];
#pragma unroll
        for (int j = 0; j < NB; ++j)
            *reinterpret_cast<short8v*>(Bs + ((j * 256 + t) << 3)) = rb[j];
        __syncthreads();
        if (k0 + 32 < K) {  // prefetch next tile, overlapped with MFMA below
#pragma unroll
            for (int j = 0; j < NA; ++j) {
                int c = j * 256 + t, row = c >> 2, ck = (c & 3) ^ ((row >> 1) & 3);
                ra[j] = *reinterpret_cast<const short8v*>(A + (size_t)(m0 + row) * sA + k0 + 32 + ck * 8);
            }
#pragma unroll
            for (int j = 0; j < NB; ++j) {
                int c = j * 256 + t, row = c >> 2, ck = (c & 3) ^ ((row >> 1) & 3);
                rb[j] = *reinterpret_cast<const short8v*>(B + (size_t)(n0 + row) * sB + k0 + 32 + ck * 8);
            }
        }
        short8v af[FM], bfr[FN];
#pragma unroll
        for (int fm = 0; fm < FM; ++fm) {
            int row = wm * (FM * 16) + fm * 16 + lr;
            int ck = g ^ ((row >> 1) & 3);
            af[fm] = *reinterpret_cast<const short8v*>(As + row * 32 + ck * 8);
        }
#pragma unroll
        for (int fn = 0; fn < FN; ++fn) {
            int col = wn * (FN * 16) + fn * 16 + lr;
            int ck = g ^ ((col >> 1) & 3);
            bfr[fn] = *reinterpret_cast<const short8v*>(Bs + col * 32 + ck * 8);
        }
#pragma unroll
        for (int fm = 0; fm < FM; ++fm)
#pragma unroll
            for (int fn = 0; fn < FN; ++fn)
                acc[fm][fn] = __builtin_amdgcn_mfma_f32_16x16x32_bf16(
                    af[fm], bfr[fn], acc[fm][fn], 0, 0, 0);
    }

#pragma unroll
    for (int fm = 0; fm < FM; ++fm) {
#pragma unroll
        for (int fn = 0; fn < FN; ++fn) {
#pragma unroll
            for (int r = 0; r < 4; ++r) {
                int row = m0 + wm * (FM * 16) + fm * 16 + g * 4 + r;
                int col = n0 + wn * (FN * 16) + fn * 16 + lr;
                float v = acc[fm][fn][r];
                if (EPI == 0) {
                    Cf[(size_t)row * N + col] = v;
                } else if (EPI == 1) {
                    Cb[(size_t)row * sCb + col] = f2bf(v);
                } else if (EPI == 2) {
                    float gs = 1.0f / (1.0f + __expf(-(v + bias[col])));
                    float zv = zf32[(size_t)row * N + col];
                    float zh = bf2f(zhbf[(size_t)row * szh + col]);
                    outf[(size_t)row * N + col] = gs * zv + (1.0f - gs) * zh;
                } else {  // EPI == 3: convT1 epilogue
                    if (row < 1568) {
                        float vv = fmaxf(v + bias[col], 0.0f);
                        int bb = row / 49, ss = row - bb * 49;
                        outf[(((size_t)bb * 4 + blockIdx.z) * 49 + ss) * 256 + col] = vv;
                    }
                }
            }
        }
    }
}

// ---------------------------------------------------------------------------
// softmax over K=512 with cosine scaling; writes attn (fp32, d_out) + bf16 copy
// ---------------------------------------------------------------------------
__global__ __launch_bounds__(256) void softmax_kernel(const float* __restrict__ dots,
                                                      const float* __restrict__ zn,
                                                      const float* __restrict__ pn,
                                                      float* __restrict__ attn,
                                                      u16* __restrict__ attn_bf) {
    int m = blockIdx.x;
    int t = threadIdx.x;
    float zm = zn[m];
    float d0 = dots[(size_t)m * 512 + t];
    float d1 = dots[(size_t)m * 512 + t + 256];
    float v0 = d0 / fmaxf(zm * pn[t], EPS_COS);
    float v1 = d1 / fmaxf(zm * pn[t + 256], EPS_COS);
    float mx = fmaxf(v0, v1);
#pragma unroll
    for (int off = 32; off > 0; off >>= 1) mx = fmaxf(mx, __shfl_down(mx, off));
    __shared__ float red[8];
    int wave = t >> 6, lane = t & 63;
    if (lane == 0) red[wave] = mx;
    __syncthreads();
    if (t == 0) red[4] = fmaxf(fmaxf(red[0], red[1]), fmaxf(red[2], red[3]));
    __syncthreads();
    mx = red[4];
    float e0 = expf(v0 - mx), e1 = expf(v1 - mx);
    float s = e0 + e1;
#pragma unroll
    for (int off = 32; off > 0; off >>= 1) s += __shfl_down(s, off);
    if (lane == 0) red[wave] = s;
    __syncthreads();
    if (t == 0) red[5] = 1.0f / (red[0] + red[1] + red[2] + red[3]);
    __syncthreads();
    float r = red[5];
    float a0 = e0 * r, a1 = e1 * r;
    attn[(size_t)m * 512 + t] = a0;
    attn[(size_t)m * 512 + t + 256] = a1;
    attn_bf[(size_t)m * 512 + t] = f2bf(a0);
    attn_bf[(size_t)m * 512 + t + 256] = f2bf(a1);
}

// ---------------------------------------------------------------------------
// pooled[b,d] = mean_n z_fused[b,n,d]
// ---------------------------------------------------------------------------
__global__ __launch_bounds__(256) void pool_kernel(const float* __restrict__ zf,
                                                   float* __restrict__ pooled) {
    int idx = blockIdx.x * 256 + threadIdx.x;  // 32768
    int b = idx >> 10, d = idx & 1023;
    const float* p = zf + (size_t)b * 196 * 1024 + d;
    float s = 0.0f;
    for (int n = 0; n < 196; ++n) s += p[(size_t)n * 1024];
    pooled[idx] = s / 196.0f;
}

// ---------------------------------------------------------------------------
// zero hp (padded bf16 h buffer [32][512][81])
// ---------------------------------------------------------------------------
__global__ __launch_bounds__(256) void hp_zero_kernel(u16* __restrict__ hp) {
    int i = blockIdx.x * 256 + threadIdx.x;  // < 165888 short8 groups
    short8v zv = {0, 0, 0, 0, 0, 0, 0, 0};
    *reinterpret_cast<short8v*>(hp + (size_t)i * 8) = zv;
}

// ---------------------------------------------------------------------------
// dec split-K phase 1: partial[kc][b][c] = sum_{k in chunk} pooled[b][k]*W[k][c]
// grid (98 col-groups, 8 k-chunks) x 256 thr; wave w owns batches w*8..w*8+7,
// thread owns 4 consecutive cols (float4 W loads, 1KB/row/wave contiguous).
// pooled chunk staged in LDS (uniform-address broadcast reads).
// ---------------------------------------------------------------------------
#define DEC_KC 128
__global__ __launch_bounds__(256) void dec_split_kernel(const float* __restrict__ pooled,
                                                        const float* __restrict__ dec_w,
                                                        float* __restrict__ partial) {
    const int t = threadIdx.x;
    const int lane = t & 63;
    const int wv = t >> 6;  // 0..3
    const int c = blockIdx.x * 256 + lane * 4;
    const int kc = blockIdx.y;
    __shared__ float pl[32][DEC_KC];
    for (int i = t; i < 32 * DEC_KC; i += 256) {
        int b = i >> 7, kk = i & (DEC_KC - 1);
        pl[b][kk] = pooled[(size_t)b * 1024 + kc * DEC_KC + kk];
    }
    __syncthreads();
    f32x4 acc[8];
#pragma unroll
    for (int j = 0; j < 8; ++j) acc[j] = (f32x4){0.f, 0.f, 0.f, 0.f};
    const float* wp = dec_w + (size_t)(kc * DEC_KC) * 25088 + c;
#pragma unroll 8
    for (int k = 0; k < DEC_KC; ++k) {
        f32x4 w4 = *reinterpret_cast<const f32x4*>(wp + (size_t)k * 25088);
#pragma unroll
        for (int j = 0; j < 8; ++j) {
            float pv = pl[wv * 8 + j][k];
            acc[j].x = fmaf(pv, w4.x, acc[j].x);
            acc[j].y = fmaf(pv, w4.y, acc[j].y);
            acc[j].z = fmaf(pv, w4.z, acc[j].z);
            acc[j].w = fmaf(pv, w4.w, acc[j].w);
        }
    }
#pragma unroll
    for (int j = 0; j < 8; ++j) {
        int b = wv * 8 + j;
        *reinterpret_cast<f32x4*>(partial + ((size_t)kc * 32 + b) * 25088 + c) = acc[j];
    }
}

// ---------------------------------------------------------------------------
// dec split-K phase 2: h[b][c] = sum_kc partial[kc][b][c] + dec_b[c],
// written bf16 into padded hp[b][ic][9][9] interior. grid (98, 32)
// ---------------------------------------------------------------------------
__global__ __launch_bounds__(256) void dec_reduce_kernel(const float* __restrict__ partial,
                                                         const float* __restrict__ dec_b,
                                                         u16* __restrict__ hp) {
    int c = blockIdx.x * 256 + threadIdx.x;
    int b = blockIdx.y;
    float s = dec_b[c];
#pragma unroll
    for (int kc = 0; kc < 8; ++kc)
        s += partial[((size_t)kc * 32 + b) * 25088 + c];
    int ic = c / 49, sp = c - ic * 49;
    int sy = sp / 7, sx = sp - sy * 7;
    hp[((size_t)b * 512 + ic) * 81 + (sy + 1) * 9 + sx + 1] = f2bf(s);
}

// ---------------------------------------------------------------------------
// im2col for convT1 parity classes: A[p][row=b*49+s][k=ic*4+tap] bf16
// tap=ty*2+tx reads hp[b][ic][sy+py-ty+1][sx+px-tx+1]; rows>=1568 zeroed
// ---------------------------------------------------------------------------
__global__ __launch_bounds__(256) void im2col_kernel(const u16* __restrict__ hp,
                                                     u16* __restrict__ A) {
    int idx = blockIdx.x * 256 + threadIdx.x;  // < 1,638,400
    int k8 = idx & 255;                        // 8 cols = 2 ic x 4 taps
    int pr = idx >> 8;
    int p = pr / 1600;
    int row = pr - p * 1600;
    short8v o = {0, 0, 0, 0, 0, 0, 0, 0};
    if (row < 1568) {
        int b = row / 49, s = row - b * 49;
        int sy = s / 7, sx = s - sy * 7;
        int r0 = sy + (p >> 1) + 1;
        int c0 = sx + (p & 1) + 1;
        int ic0 = k8 * 2;
        const u16* hb = hp + ((size_t)b * 512 + ic0) * 81;
#pragma unroll
        for (int j = 0; j < 2; ++j) {
            o[j * 4 + 0] = hb[r0 * 9 + c0];
            o[j * 4 + 1] = hb[r0 * 9 + c0 - 1];
            o[j * 4 + 2] = hb[(r0 - 1) * 9 + c0];
            o[j * 4 + 3] = hb[(r0 - 1) * 9 + c0 - 1];
            hb += 81;
        }
    }
    *reinterpret_cast<short8v*>(A + (size_t)idx * 8) = o;
}

// ---------------------------------------------------------------------------
// ct1_w [512][256][4][4] -> wt1bf [p=4][oc=256][k=ic*4+tap] bf16
// ---------------------------------------------------------------------------
__global__ __launch_bounds__(256) void wtrans_kernel(const float* __restrict__ wsrc,
                                                     u16* __restrict__ wt) {
    int idx = blockIdx.x * 256 + threadIdx.x;  // ic*256+oc
    int oc = idx & 255, ic = idx >> 8;
    float v[16];
#pragma unroll
    for (int i = 0; i < 16; ++i) v[i] = wsrc[(size_t)idx * 16 + i];
#pragma unroll
    for (int pp = 0; pp < 4; ++pp) {
        int py = pp >> 1, px = pp & 1;
#pragma unroll
        for (int tap = 0; tap < 4; ++tap) {
            int ty = tap >> 1, tx = tap & 1;
            int ky = (1 - py) + 2 * ty;
            int kx = (1 - px) + 2 * tx;
            wt[((size_t)(pp * 256 + oc)) * 2048 + ic * 4 + tap] = f2bf(v[ky * 4 + kx]);
        }
    }
}

// ---------------------------------------------------------------------------
// ct2_w [256][3][4][4] -> w2t [oc=3][ky=4][kx=4][ic=256] (ic-contiguous fp32)
// ---------------------------------------------------------------------------
__global__ __launch_bounds__(256) void w2trans_kernel(const float* __restrict__ w,
                                                      float* __restrict__ w2t) {
    int idx = blockIdx.x * 256 + threadIdx.x;  // < 12288
    int ic = idx & 255;
    int r = idx >> 8;  // oc*16 + ky*4 + kx
    int kx = r & 3, ky = (r >> 2) & 3, oc = r >> 4;
    w2t[idx] = w[((size_t)ic * 3 + oc) * 16 + ky * 4 + kx];
}

// ---------------------------------------------------------------------------
// ConvTranspose2d(256->3,k4,s2,p1)+bias from h2c [b][p][49][ic=256] fp32
// ---------------------------------------------------------------------------
__global__ __launch_bounds__(256) void convt2_kernel(const float* __restrict__ h2c,
                                                     const float* __restrict__ w2t,
                                                     const float* __restrict__ bias,
                                                     float* __restrict__ out) {
    int o = blockIdx.x * 256 + threadIdx.x;  // < 75264
    int ox = o % 28;
    int oy = (o / 28) % 28;
    int oc = (o / 784) % 3;
    int b = o / 2352;
    int by = (oy + 1) >> 1, bx = (ox + 1) >> 1;
    float acc = bias[oc];
#pragma unroll
    for (int ty = 0; ty < 2; ++ty) {
        int iy = by - ty;
        if ((unsigned)iy >= 14u) continue;
#pragma unroll
        for (int tx = 0; tx < 2; ++tx) {
            int ix = bx - tx;
            if ((unsigned)ix >= 14u) continue;
            int p = (iy & 1) * 2 + (ix & 1);
            int sy = iy >> 1, sx = ix >> 1;
            int ky = oy + 1 - 2 * iy, kx = ox + 1 - 2 * ix;
            const float* hb = h2c + (((size_t)b * 4 + p) * 49 + sy * 7 + sx) * 256;
            const float* wb = w2t + ((oc * 4 + ky) * 4 + kx) * 256;
            for (int i = 0; i < 256; i += 4) {
                float4 h4 = *reinterpret_cast<const float4*>(hb + i);
                float4 w4 = *reinterpret_cast<const float4*>(wb + i);
                acc = fmaf(h4.x, w4.x, acc);
                acc = fmaf(h4.y, w4.y, acc);
                acc = fmaf(h4.z, w4.z, acc);
                acc = fmaf(h4.w, w4.w, acc);
            }
        }
    }
    out[o] = acc;
}

// ---------------------------------------------------------------------------
extern "C" void kernel_launch(void* const* d_in, const int* in_sizes, int n_in,
                              void* d_out, int out_size, void* d_ws, size_t ws_size,
                              hipStream_t stream) {
    const float* z      = (const float*)d_in[0];  // [32,196,1024]
    const float* protos = (const float*)d_in[1];  // [512,1024]
    const float* gate_w = (const float*)d_in[2];  // [2048,1024]
    const float* gate_b = (const float*)d_in[3];  // [1024]
    const float* dec_w  = (const float*)d_in[4];  // [1024,25088]
    const float* dec_b  = (const float*)d_in[5];  // [25088]
    const float* ct1_w  = (const float*)d_in[6];  // [512,256,4,4]
    const float* ct1_b  = (const float*)d_in[7];  // [256]
    const float* ct2_w  = (const float*)d_in[8];  // [256,3,4,4]
    const float* ct2_b  = (const float*)d_in[9];  // [3]

    float* xout = (float*)d_out;   // x_recon 75264
    float* attn = xout + 75264;    // attn 3211264

    float* w = (float*)d_ws;
    float* pn        = w;                       // 512
    float* zn        = w + 512;                 // 6272
    float* pooled    = w + 6784;                // 32768
    float* w2t       = w + 39552;               // 12288
    u16*   wt1bf     = (u16*)(w + 51840);       // 2,097,152 u16 -> ends 1,100,416
    u16*   protos_bf = (u16*)(w + 1100416);     // 524288 u16
    u16*   protosT   = (u16*)(w + 1362560);     // 524288 u16
    u16*   gwT       = (u16*)(w + 1624704);     // 2,097,152 u16 -> ends 2,673,280
    u16*   attn_bf   = (u16*)(w + 2673280);     // 3,211,264 u16
    u16*   Abig      = (u16*)(w + 4278912);     // [6272][2048] u16 -> ends 10,701,440
    u16*   A_cls     = (u16*)(w + 2673280);     // overlay attn_bf+Abig (dead by im2col)
    float* dots      = w + 10701440;            // 3,211,264
    float* z_fused   = w + 10701440;            // overlays dots (dead after softmax);
                                                //   spans .. 17,123,968
    float* partial   = w + 10701440;            // overlays z_fused (dead after pool);
                                                //   [8][32][25088] = 6,422,528 floats
    float* h2c       = w + 11364992;            // overlays partial (dead after dec_reduce;
                                                //   h2c written only by convt1 GEMM after)
    u16*   hp        = (u16*)(w + 17123968);    // NON-overlapping zero-padded h buffer
                                                //   -> ends 17,787,520 (71.2MB)

    // operand prep
    hp_zero_kernel<<<648, 256, 0, stream>>>(hp);
    cvt_bf_kernel<<<3136, 256, 0, stream>>>(z, Abig, 1024, 2048, 6422528);
    cvt_bf_kernel<<<256, 256, 0, stream>>>(protos, protos_bf, 1024, 1024, 524288);
    transpose_cvt_kernel<<<dim3(16, 8), 256, 0, stream>>>(protos, protosT, 512, 1024);
    transpose_cvt_kernel<<<dim3(16, 32), 256, 0, stream>>>(gate_w, gwT, 2048, 1024);
    wtrans_kernel<<<512, 256, 0, stream>>>(ct1_w, wt1bf);
    w2trans_kernel<<<48, 256, 0, stream>>>(ct2_w, w2t);
    // norms
    norm_rows_kernel<<<512, 256, 0, stream>>>(protos, pn);
    norm_rows_kernel<<<6272, 256, 0, stream>>>(z, zn);
    // dots = z @ protos^T  (M=6272, N=512, K=1024)
    mfma_gemm_kernel<2, 4, 0><<<dim3(98, 4), 256, 0, stream>>>(
        Abig, 2048, 0, protos_bf, 1024, 0, 6272, 512, 1024,
        dots, nullptr, 0, nullptr, nullptr, nullptr, 0, nullptr);
    // softmax -> attn (fp32 out) + attn_bf
    softmax_kernel<<<6272, 256, 0, stream>>>(dots, zn, pn, attn, attn_bf);
    // z_hat = attn @ protos (M=6272, N=1024, K=512) -> bf16 into Abig right half
    mfma_gemm_kernel<4, 4, 1><<<dim3(49, 8), 256, 0, stream>>>(
        attn_bf, 512, 0, protosT, 512, 0, 6272, 1024, 512,
        nullptr, Abig + 1024, 2048, nullptr, nullptr, nullptr, 0, nullptr);
    // gate GEMM (K=2048) + sigmoid blend -> z_fused
    mfma_gemm_kernel<4, 4, 2><<<dim3(49, 8), 256, 0, stream>>>(
        Abig, 2048, 0, gwT, 2048, 0, 6272, 1024, 2048,
        nullptr, nullptr, 0, gate_b, z, Abig + 1024, 2048, z_fused);
    // pool -> decoder (split-K streaming GEMV, partials overlay dead z_fused)
    pool_kernel<<<128, 256, 0, stream>>>(z_fused, pooled);
    dec_split_kernel<<<dim3(98, 8), 256, 0, stream>>>(pooled, dec_w, partial);
    dec_reduce_kernel<<<dim3(98, 32), 256, 0, stream>>>(partial, dec_b, hp);
    // convT1 as grouped MFMA GEMM: im2col then 4-class GEMM + bias/relu epilogue
    im2col_kernel<<<6400, 256, 0, stream>>>(hp, A_cls);
    mfma_gemm_kernel<2, 2, 3><<<dim3(25, 4, 4), 256, 0, stream>>>(
        A_cls, 2048, (size_t)1600 * 2048, wt1bf, 2048, (size_t)256 * 2048,
        1600, 256, 2048, nullptr, nullptr, 0, ct1_b, nullptr, nullptr, 0, h2c);
    // convT2 -> x_recon
    convt2_kernel<<<294, 256, 0, stream>>>(h2c, w2t, ct2_b, xout);
}

// Round 6
// 237.669 us; speedup vs baseline: 5.6474x; 1.2638x over previous
//
#include <hip/hip_runtime.h>
#include <cstdint>
#include <cstddef>
#include <cmath>

#define EPS_COS 1e-8f

typedef unsigned short u16;
typedef __attribute__((ext_vector_type(8))) short short8v;
typedef __attribute__((ext_vector_type(4))) float f32x4;

__device__ __forceinline__ u16 f2bf(float x) {
    unsigned int u = __float_as_uint(x);
    return (u16)((u + 0x7FFFu + ((u >> 16) & 1u)) >> 16);  // RNE
}
__device__ __forceinline__ float bf2f(u16 h) {
    return __uint_as_float(((unsigned int)h) << 16);
}

// ---------------------------------------------------------------------------
// row L2 norms (C fixed = 1024)
// ---------------------------------------------------------------------------
__global__ __launch_bounds__(256) void norm_rows_kernel(const float* __restrict__ X,
                                                        float* __restrict__ out) {
    int r = blockIdx.x;
    int t = threadIdx.x;
    const float4 v = *reinterpret_cast<const float4*>(&X[(size_t)r * 1024 + t * 4]);
    float ss = v.x * v.x + v.y * v.y + v.z * v.z + v.w * v.w;
#pragma unroll
    for (int off = 32; off > 0; off >>= 1) ss += __shfl_down(ss, off);
    __shared__ float red[4];
    int wave = t >> 6, lane = t & 63;
    if (lane == 0) red[wave] = ss;
    __syncthreads();
    if (t == 0) out[r] = sqrtf(red[0] + red[1] + red[2] + red[3]);
}

// ---------------------------------------------------------------------------
// fp32 -> bf16 copy (row-strided dst), 8 elems/thread
// ---------------------------------------------------------------------------
__global__ __launch_bounds__(256) void cvt_bf_kernel(const float* __restrict__ src,
                                                     u16* __restrict__ dst,
                                                     int srcW, int dstStride, int nElem) {
    int idx = blockIdx.x * 256 + threadIdx.x;
    int e = idx * 8;
    if (e >= nElem) return;
    float4 v0 = *reinterpret_cast<const float4*>(src + e);
    float4 v1 = *reinterpret_cast<const float4*>(src + e + 4);
    int row = e / srcW, col = e - row * srcW;
    u16* d = dst + (size_t)row * dstStride + col;
    short8v o;
    o[0] = f2bf(v0.x); o[1] = f2bf(v0.y); o[2] = f2bf(v0.z); o[3] = f2bf(v0.w);
    o[4] = f2bf(v1.x); o[5] = f2bf(v1.y); o[6] = f2bf(v1.z); o[7] = f2bf(v1.w);
    *reinterpret_cast<short8v*>(d) = o;
}

// ---------------------------------------------------------------------------
// transpose + cvt: src [R][C] f32 -> dst [C][R] bf16 (64x64 LDS tiles, +1 pad)
// ---------------------------------------------------------------------------
__global__ __launch_bounds__(256) void transpose_cvt_kernel(const float* __restrict__ src,
                                                            u16* __restrict__ dst,
                                                            int R, int C) {
    __shared__ float tile[64][65];
    int c0 = blockIdx.x * 64, r0 = blockIdx.y * 64;
    int t = threadIdx.x;
#pragma unroll
    for (int j = 0; j < 16; ++j) {
        int idx = j * 256 + t;
        int r = idx >> 6, c = idx & 63;
        tile[r][c] = src[(size_t)(r0 + r) * C + c0 + c];
    }
    __syncthreads();
#pragma unroll
    for (int j = 0; j < 16; ++j) {
        int idx = j * 256 + t;
        int c = idx >> 6, r = idx & 63;
        dst[(size_t)(c0 + c) * R + r0 + r] = f2bf(tile[r][c]);
    }
}

// ---------------------------------------------------------------------------
// bf16 MFMA GEMM, all-NT: C[M,N] = A[M,K(sA)] * B[N,K(sB)]^T
// blockIdx.z selects a (A,B) pair via zsA/zsB element strides (grouped GEMM).
// BM = FM*32, BN = FN*32; 4 waves (2x2), wave tile (FM*16) x (FN*16).
// LDS: [row][32 k] bf16, 16B chunks XOR-swizzled: ck' = ck ^ ((row>>1)&3).
// EPI 0: fp32 store to Cf[M][N]
// EPI 1: bf16 store to Cb[row*sCb + col]
// EPI 2: g=sigmoid(acc+bias[col]); outf = g*z + (1-g)*z_hat (z fp32, z_hat bf16)
// EPI 3: relu(acc+bias[col]) -> bf16 Cb[((b*4+z)*49+s)*256 + col], row=b*49+s<1568
// ---------------------------------------------------------------------------
template <int FM, int FN, int EPI>
__global__ __launch_bounds__(256) void mfma_gemm_kernel(
    const u16* __restrict__ A, int sA, size_t zsA,
    const u16* __restrict__ B, int sB, size_t zsB,
    int M, int N, int K,
    float* __restrict__ Cf,
    u16* __restrict__ Cb, int sCb,
    const float* __restrict__ bias,
    const float* __restrict__ zf32,
    const u16* __restrict__ zhbf, int szh,
    float* __restrict__ outf) {
    constexpr int BM = FM * 32, BN = FN * 32;
    constexpr int NA = (BM * 4) / 256;  // 16B chunks per thread (A)
    constexpr int NB = (BN * 4) / 256;
    __shared__ __align__(16) u16 As[BM * 32];
    __shared__ __align__(16) u16 Bs[BN * 32];
    A += (size_t)blockIdx.z * zsA;
    B += (size_t)blockIdx.z * zsB;
    const int t = threadIdx.x;
    const int lane = t & 63;
    const int wid = t >> 6;
    const int wm = wid >> 1, wn = wid & 1;
    const int m0 = blockIdx.x * BM, n0 = blockIdx.y * BN;
    const int g = lane >> 4, lr = lane & 15;

    f32x4 acc[FM][FN];
#pragma unroll
    for (int i = 0; i < FM; ++i)
#pragma unroll
        for (int j = 0; j < FN; ++j) acc[i][j] = (f32x4){0.f, 0.f, 0.f, 0.f};

    short8v ra[NA], rb[NB];
#pragma unroll
    for (int j = 0; j < NA; ++j) {
        int c = j * 256 + t, row = c >> 2, ck = (c & 3) ^ ((row >> 1) & 3);
        ra[j] = *reinterpret_cast<const short8v*>(A + (size_t)(m0 + row) * sA + ck * 8);
    }
#pragma unroll
    for (int j = 0; j < NB; ++j) {
        int c = j * 256 + t, row = c >> 2, ck = (c & 3) ^ ((row >> 1) & 3);
        rb[j] = *reinterpret_cast<const short8v*>(B + (size_t)(n0 + row) * sB + ck * 8);
    }

    for (int k0 = 0; k0 < K; k0 += 32) {
        __syncthreads();
#pragma unroll
        for (int j = 0; j < NA; ++j)
            *reinterpret_cast<short8v*>(As + ((j * 256 + t) << 3)) = ra[j];
#pragma unroll
        for (int j = 0; j < NB; ++j)
            *reinterpret_cast<short8v*>(Bs + ((j * 256 + t) << 3)) = rb[j];
        __syncthreads();
        if (k0 + 32 < K) {  // prefetch next tile, overlapped with MFMA below
#pragma unroll
            for (int j = 0; j < NA; ++j) {
                int c = j * 256 + t, row = c >> 2, ck = (c & 3) ^ ((row >> 1) & 3);
                ra[j] = *reinterpret_cast<const short8v*>(A + (size_t)(m0 + row) * sA + k0 + 32 + ck * 8);
            }
#pragma unroll
            for (int j = 0; j < NB; ++j) {
                int c = j * 256 + t, row = c >> 2, ck = (c & 3) ^ ((row >> 1) & 3);
                rb[j] = *reinterpret_cast<const short8v*>(B + (size_t)(n0 + row) * sB + k0 + 32 + ck * 8);
            }
        }
        short8v af[FM], bfr[FN];
#pragma unroll
        for (int fm = 0; fm < FM; ++fm) {
            int row = wm * (FM * 16) + fm * 16 + lr;
            int ck = g ^ ((row >> 1) & 3);
            af[fm] = *reinterpret_cast<const short8v*>(As + row * 32 + ck * 8);
        }
#pragma unroll
        for (int fn = 0; fn < FN; ++fn) {
            int col = wn * (FN * 16) + fn * 16 + lr;
            int ck = g ^ ((col >> 1) & 3);
            bfr[fn] = *reinterpret_cast<const short8v*>(Bs + col * 32 + ck * 8);
        }
#pragma unroll
        for (int fm = 0; fm < FM; ++fm)
#pragma unroll
            for (int fn = 0; fn < FN; ++fn)
                acc[fm][fn] = __builtin_amdgcn_mfma_f32_16x16x32_bf16(
                    af[fm], bfr[fn], acc[fm][fn], 0, 0, 0);
    }

#pragma unroll
    for (int fm = 0; fm < FM; ++fm) {
#pragma unroll
        for (int fn = 0; fn < FN; ++fn) {
#pragma unroll
            for (int r = 0; r < 4; ++r) {
                int row = m0 + wm * (FM * 16) + fm * 16 + g * 4 + r;
                int col = n0 + wn * (FN * 16) + fn * 16 + lr;
                float v = acc[fm][fn][r];
                if (EPI == 0) {
                    Cf[(size_t)row * N + col] = v;
                } else if (EPI == 1) {
                    Cb[(size_t)row * sCb + col] = f2bf(v);
                } else if (EPI == 2) {
                    float gs = 1.0f / (1.0f + __expf(-(v + bias[col])));
                    float zv = zf32[(size_t)row * N + col];
                    float zh = bf2f(zhbf[(size_t)row * szh + col]);
                    outf[(size_t)row * N + col] = gs * zv + (1.0f - gs) * zh;
                } else {  // EPI == 3: convT1 epilogue -> bf16 h2cb
                    if (row < 1568) {
                        float vv = fmaxf(v + bias[col], 0.0f);
                        int bb = row / 49, ss = row - bb * 49;
                        Cb[(((size_t)bb * 4 + blockIdx.z) * 49 + ss) * 256 + col] = f2bf(vv);
                    }
                }
            }
        }
    }
}

// ---------------------------------------------------------------------------
// softmax over K=512 with cosine scaling; writes attn (fp32, d_out) + bf16 copy
// ---------------------------------------------------------------------------
__global__ __launch_bounds__(256) void softmax_kernel(const float* __restrict__ dots,
                                                      const float* __restrict__ zn,
                                                      const float* __restrict__ pn,
                                                      float* __restrict__ attn,
                                                      u16* __restrict__ attn_bf) {
    int m = blockIdx.x;
    int t = threadIdx.x;
    float zm = zn[m];
    float d0 = dots[(size_t)m * 512 + t];
    float d1 = dots[(size_t)m * 512 + t + 256];
    float v0 = d0 / fmaxf(zm * pn[t], EPS_COS);
    float v1 = d1 / fmaxf(zm * pn[t + 256], EPS_COS);
    float mx = fmaxf(v0, v1);
#pragma unroll
    for (int off = 32; off > 0; off >>= 1) mx = fmaxf(mx, __shfl_down(mx, off));
    __shared__ float red[8];
    int wave = t >> 6, lane = t & 63;
    if (lane == 0) red[wave] = mx;
    __syncthreads();
    if (t == 0) red[4] = fmaxf(fmaxf(red[0], red[1]), fmaxf(red[2], red[3]));
    __syncthreads();
    mx = red[4];
    float e0 = expf(v0 - mx), e1 = expf(v1 - mx);
    float s = e0 + e1;
#pragma unroll
    for (int off = 32; off > 0; off >>= 1) s += __shfl_down(s, off);
    if (lane == 0) red[wave] = s;
    __syncthreads();
    if (t == 0) red[5] = 1.0f / (red[0] + red[1] + red[2] + red[3]);
    __syncthreads();
    float r = red[5];
    float a0 = e0 * r, a1 = e1 * r;
    attn[(size_t)m * 512 + t] = a0;
    attn[(size_t)m * 512 + t + 256] = a1;
    attn_bf[(size_t)m * 512 + t] = f2bf(a0);
    attn_bf[(size_t)m * 512 + t + 256] = f2bf(a1);
}

// ---------------------------------------------------------------------------
// pooled[b,d] = mean_n z_fused[b,n,d]
// ---------------------------------------------------------------------------
__global__ __launch_bounds__(256) void pool_kernel(const float* __restrict__ zf,
                                                   float* __restrict__ pooled) {
    int idx = blockIdx.x * 256 + threadIdx.x;  // 32768
    int b = idx >> 10, d = idx & 1023;
    const float* p = zf + (size_t)b * 196 * 1024 + d;
    float s = 0.0f;
    for (int n = 0; n < 196; ++n) s += p[(size_t)n * 1024];
    pooled[idx] = s / 196.0f;
}

// ---------------------------------------------------------------------------
// zero hp (padded bf16 h buffer [32][512][81])
// ---------------------------------------------------------------------------
__global__ __launch_bounds__(256) void hp_zero_kernel(u16* __restrict__ hp) {
    int i = blockIdx.x * 256 + threadIdx.x;  // < 165888 short8 groups
    short8v zv = {0, 0, 0, 0, 0, 0, 0, 0};
    *reinterpret_cast<short8v*>(hp + (size_t)i * 8) = zv;
}

// ---------------------------------------------------------------------------
// dec split-K phase 1: partial[kc][b][c] = sum_{k in chunk} pooled[b][k]*W[k][c]
// ---------------------------------------------------------------------------
#define DEC_KC 128
__global__ __launch_bounds__(256) void dec_split_kernel(const float* __restrict__ pooled,
                                                        const float* __restrict__ dec_w,
                                                        float* __restrict__ partial) {
    const int t = threadIdx.x;
    const int lane = t & 63;
    const int wv = t >> 6;  // 0..3
    const int c = blockIdx.x * 256 + lane * 4;
    const int kc = blockIdx.y;
    __shared__ float pl[32][DEC_KC];
    for (int i = t; i < 32 * DEC_KC; i += 256) {
        int b = i >> 7, kk = i & (DEC_KC - 1);
        pl[b][kk] = pooled[(size_t)b * 1024 + kc * DEC_KC + kk];
    }
    __syncthreads();
    f32x4 acc[8];
#pragma unroll
    for (int j = 0; j < 8; ++j) acc[j] = (f32x4){0.f, 0.f, 0.f, 0.f};
    const float* wp = dec_w + (size_t)(kc * DEC_KC) * 25088 + c;
#pragma unroll 8
    for (int k = 0; k < DEC_KC; ++k) {
        f32x4 w4 = *reinterpret_cast<const f32x4*>(wp + (size_t)k * 25088);
#pragma unroll
        for (int j = 0; j < 8; ++j) {
            float pv = pl[wv * 8 + j][k];
            acc[j].x = fmaf(pv, w4.x, acc[j].x);
            acc[j].y = fmaf(pv, w4.y, acc[j].y);
            acc[j].z = fmaf(pv, w4.z, acc[j].z);
            acc[j].w = fmaf(pv, w4.w, acc[j].w);
        }
    }
#pragma unroll
    for (int j = 0; j < 8; ++j) {
        int b = wv * 8 + j;
        *reinterpret_cast<f32x4*>(partial + ((size_t)kc * 32 + b) * 25088 + c) = acc[j];
    }
}

// ---------------------------------------------------------------------------
// dec split-K phase 2: h[b][c] = sum_kc partial[kc][b][c] + dec_b[c] -> bf16 hp
// ---------------------------------------------------------------------------
__global__ __launch_bounds__(256) void dec_reduce_kernel(const float* __restrict__ partial,
                                                         const float* __restrict__ dec_b,
                                                         u16* __restrict__ hp) {
    int c = blockIdx.x * 256 + threadIdx.x;
    int b = blockIdx.y;
    float s = dec_b[c];
#pragma unroll
    for (int kc = 0; kc < 8; ++kc)
        s += partial[((size_t)kc * 32 + b) * 25088 + c];
    int ic = c / 49, sp = c - ic * 49;
    int sy = sp / 7, sx = sp - sy * 7;
    hp[((size_t)b * 512 + ic) * 81 + (sy + 1) * 9 + sx + 1] = f2bf(s);
}

// ---------------------------------------------------------------------------
// im2col for convT1 parity classes: A[p][row=b*49+s][k=ic*4+tap] bf16
// ---------------------------------------------------------------------------
__global__ __launch_bounds__(256) void im2col_kernel(const u16* __restrict__ hp,
                                                     u16* __restrict__ A) {
    int idx = blockIdx.x * 256 + threadIdx.x;  // < 1,638,400
    int k8 = idx & 255;                        // 8 cols = 2 ic x 4 taps
    int pr = idx >> 8;
    int p = pr / 1600;
    int row = pr - p * 1600;
    short8v o = {0, 0, 0, 0, 0, 0, 0, 0};
    if (row < 1568) {
        int b = row / 49, s = row - b * 49;
        int sy = s / 7, sx = s - sy * 7;
        int r0 = sy + (p >> 1) + 1;
        int c0 = sx + (p & 1) + 1;
        int ic0 = k8 * 2;
        const u16* hb = hp + ((size_t)b * 512 + ic0) * 81;
#pragma unroll
        for (int j = 0; j < 2; ++j) {
            o[j * 4 + 0] = hb[r0 * 9 + c0];
            o[j * 4 + 1] = hb[r0 * 9 + c0 - 1];
            o[j * 4 + 2] = hb[(r0 - 1) * 9 + c0];
            o[j * 4 + 3] = hb[(r0 - 1) * 9 + c0 - 1];
            hb += 81;
        }
    }
    *reinterpret_cast<short8v*>(A + (size_t)idx * 8) = o;
}

// ---------------------------------------------------------------------------
// ct1_w [512][256][4][4] -> wt1bf [p=4][oc=256][k=ic*4+tap] bf16
// ---------------------------------------------------------------------------
__global__ __launch_bounds__(256) void wtrans_kernel(const float* __restrict__ wsrc,
                                                     u16* __restrict__ wt) {
    int idx = blockIdx.x * 256 + threadIdx.x;  // ic*256+oc
    int oc = idx & 255, ic = idx >> 8;
    float v[16];
#pragma unroll
    for (int i = 0; i < 16; ++i) v[i] = wsrc[(size_t)idx * 16 + i];
#pragma unroll
    for (int pp = 0; pp < 4; ++pp) {
        int py = pp >> 1, px = pp & 1;
#pragma unroll
        for (int tap = 0; tap < 4; ++tap) {
            int ty = tap >> 1, tx = tap & 1;
            int ky = (1 - py) + 2 * ty;
            int kx = (1 - px) + 2 * tx;
            wt[((size_t)(pp * 256 + oc)) * 2048 + ic * 4 + tap] = f2bf(v[ky * 4 + kx]);
        }
    }
}

// ---------------------------------------------------------------------------
// ct2_w [256][3][4][4] -> Wpad[col=64][ic=256] bf16 NT; col=oc*16+ky*4+kx (<48)
// ---------------------------------------------------------------------------
__global__ __launch_bounds__(256) void wpad_kernel(const float* __restrict__ w,
                                                   u16* __restrict__ wpad) {
    int idx = blockIdx.x * 256 + threadIdx.x;  // < 16384
    int ic = idx & 255;
    int col = idx >> 8;
    float v = 0.0f;
    if (col < 48) {
        int kx = col & 3, ky = (col >> 2) & 3, oc = col >> 4;
        v = w[((size_t)ic * 3 + oc) * 16 + ky * 4 + kx];
    }
    wpad[idx] = f2bf(v);
}

// ---------------------------------------------------------------------------
// convT2 gather: out[o] = bias[oc] + sum_{<=4 taps} G[row][oc*16+ky*4+kx]
// G [6272][64] fp32, row = (b*4+p)*49 + sy*7+sx  (same mapping as before)
// ---------------------------------------------------------------------------
__global__ __launch_bounds__(256) void convt2_gather_kernel(const float* __restrict__ G,
                                                            const float* __restrict__ bias,
                                                            float* __restrict__ out) {
    int o = blockIdx.x * 256 + threadIdx.x;  // < 75264
    int ox = o % 28;
    int oy = (o / 28) % 28;
    int oc = (o / 784) % 3;
    int b = o / 2352;
    int by = (oy + 1) >> 1, bx = (ox + 1) >> 1;
    float acc = bias[oc];
#pragma unroll
    for (int ty = 0; ty < 2; ++ty) {
        int iy = by - ty;
        if ((unsigned)iy >= 14u) continue;
#pragma unroll
        for (int tx = 0; tx < 2; ++tx) {
            int ix = bx - tx;
            if ((unsigned)ix >= 14u) continue;
            int p = (iy & 1) * 2 + (ix & 1);
            int row = ((b * 4 + p) * 49) + (iy >> 1) * 7 + (ix >> 1);
            int ky = oy + 1 - 2 * iy, kx = ox + 1 - 2 * ix;
            acc += G[(size_t)row * 64 + oc * 16 + ky * 4 + kx];
        }
    }
    out[o] = acc;
}

// ---------------------------------------------------------------------------
extern "C" void kernel_launch(void* const* d_in, const int* in_sizes, int n_in,
                              void* d_out, int out_size, void* d_ws, size_t ws_size,
                              hipStream_t stream) {
    const float* z      = (const float*)d_in[0];  // [32,196,1024]
    const float* protos = (const float*)d_in[1];  // [512,1024]
    const float* gate_w = (const float*)d_in[2];  // [2048,1024]
    const float* gate_b = (const float*)d_in[3];  // [1024]
    const float* dec_w  = (const float*)d_in[4];  // [1024,25088]
    const float* dec_b  = (const float*)d_in[5];  // [25088]
    const float* ct1_w  = (const float*)d_in[6];  // [512,256,4,4]
    const float* ct1_b  = (const float*)d_in[7];  // [256]
    const float* ct2_w  = (const float*)d_in[8];  // [256,3,4,4]
    const float* ct2_b  = (const float*)d_in[9];  // [3]

    float* xout = (float*)d_out;   // x_recon 75264
    float* attn = xout + 75264;    // attn 3211264

    float* w = (float*)d_ws;
    float* pn        = w;                       // 512
    float* zn        = w + 512;                 // 6272
    float* pooled    = w + 6784;                // 32768
    u16*   wt1bf     = (u16*)(w + 51840);       // 2,097,152 u16 -> ends 1,100,416
    u16*   protos_bf = (u16*)(w + 1100416);     // 524288 u16
    u16*   protosT   = (u16*)(w + 1362560);     // 524288 u16
    u16*   gwT       = (u16*)(w + 1624704);     // 2,097,152 u16 -> ends 2,673,280
    u16*   attn_bf   = (u16*)(w + 2673280);     // 3,211,264 u16
    u16*   Abig      = (u16*)(w + 4278912);     // [6272][2048] u16 -> ends 10,701,440
    u16*   A_cls     = (u16*)(w + 2673280);     // overlay attn_bf+Abig (dead by im2col)
    float* dots      = w + 10701440;            // 3,211,264
    float* z_fused   = w + 10701440;            // overlays dots (dead after softmax);
                                                //   spans .. 17,123,968
    float* partial   = w + 10701440;            // overlays z_fused (dead after pool)
    u16*   h2cb      = (u16*)(w + 11364992);    // bf16 [6272][256]; overlays partial
                                                //   (partial dead before convt1 GEMM)
    u16*   hp        = (u16*)(w + 17123968);    // zero-padded h buffer -> ends 17,787,520
    float* G         = w + 17787520;            // [6272][64] fp32 -> ends 18,188,928
    u16*   wpad      = (u16*)(w + 18188928);    // [64][256] bf16 -> ends 18,197,120 (72.8MB)

    // operand prep
    hp_zero_kernel<<<648, 256, 0, stream>>>(hp);
    cvt_bf_kernel<<<3136, 256, 0, stream>>>(z, Abig, 1024, 2048, 6422528);
    cvt_bf_kernel<<<256, 256, 0, stream>>>(protos, protos_bf, 1024, 1024, 524288);
    transpose_cvt_kernel<<<dim3(16, 8), 256, 0, stream>>>(protos, protosT, 512, 1024);
    transpose_cvt_kernel<<<dim3(16, 32), 256, 0, stream>>>(gate_w, gwT, 2048, 1024);
    wtrans_kernel<<<512, 256, 0, stream>>>(ct1_w, wt1bf);
    wpad_kernel<<<64, 256, 0, stream>>>(ct2_w, wpad);
    // norms
    norm_rows_kernel<<<512, 256, 0, stream>>>(protos, pn);
    norm_rows_kernel<<<6272, 256, 0, stream>>>(z, zn);
    // dots = z @ protos^T  (M=6272, N=512, K=1024)
    mfma_gemm_kernel<2, 4, 0><<<dim3(98, 4), 256, 0, stream>>>(
        Abig, 2048, 0, protos_bf, 1024, 0, 6272, 512, 1024,
        dots, nullptr, 0, nullptr, nullptr, nullptr, 0, nullptr);
    // softmax -> attn (fp32 out) + attn_bf
    softmax_kernel<<<6272, 256, 0, stream>>>(dots, zn, pn, attn, attn_bf);
    // z_hat = attn @ protos (M=6272, N=1024, K=512) -> bf16 into Abig right half
    mfma_gemm_kernel<4, 4, 1><<<dim3(49, 8), 256, 0, stream>>>(
        attn_bf, 512, 0, protosT, 512, 0, 6272, 1024, 512,
        nullptr, Abig + 1024, 2048, nullptr, nullptr, nullptr, 0, nullptr);
    // gate GEMM (K=2048) + sigmoid blend -> z_fused
    mfma_gemm_kernel<4, 4, 2><<<dim3(49, 8), 256, 0, stream>>>(
        Abig, 2048, 0, gwT, 2048, 0, 6272, 1024, 2048,
        nullptr, nullptr, 0, gate_b, z, Abig + 1024, 2048, z_fused);
    // pool -> decoder (split-K streaming GEMV)
    pool_kernel<<<128, 256, 0, stream>>>(z_fused, pooled);
    dec_split_kernel<<<dim3(98, 8), 256, 0, stream>>>(pooled, dec_w, partial);
    dec_reduce_kernel<<<dim3(98, 32), 256, 0, stream>>>(partial, dec_b, hp);
    // convT1 as grouped MFMA GEMM (epilogue writes bf16 h2cb)
    im2col_kernel<<<6400, 256, 0, stream>>>(hp, A_cls);
    mfma_gemm_kernel<2, 2, 3><<<dim3(25, 4, 4), 256, 0, stream>>>(
        A_cls, 2048, (size_t)1600 * 2048, wt1bf, 2048, (size_t)256 * 2048,
        1600, 256, 2048, nullptr, h2cb, 0, ct1_b, nullptr, nullptr, 0, nullptr);
    // convT2 as GEMM (M=6272, N=64, K=256) + gather
    mfma_gemm_kernel<2, 2, 0><<<dim3(98, 1), 256, 0, stream>>>(
        h2cb, 256, 0, wpad, 256, 0, 6272, 64, 256,
        G, nullptr, 0, nullptr, nullptr, nullptr, 0, nullptr);
    convt2_gather_kernel<<<294, 256, 0, stream>>>(G, ct2_b, xout);
}